// Round 2
// baseline (5169.586 us; speedup 1.0000x reference)
//
#include <hip/hip_runtime.h>

#define NDATA 131072
#define NHID  32768
#define NEDGE 524288

__device__ __forceinline__ float gelu_f(float x) {
    return 0.5f * x * (1.0f + erff(x * 0.7071067811865476f));
}

// out[n,256] = gelu(x[n,K] @ w[256,K]^T + b)   (small-K encoder)
template<int K>
__global__ __launch_bounds__(256)
void enc_kernel(const float* __restrict__ x, const float* __restrict__ w,
                const float* __restrict__ b, float* __restrict__ out, int n) {
    __shared__ float ws[K * 256];   // transposed: ws[j][f]
    const int t = threadIdx.x;
    #pragma unroll
    for (int j = 0; j < K; ++j) ws[j * 256 + t] = w[t * K + j];
    const float bias = b[t];
    __syncthreads();
    for (int node = blockIdx.x; node < n; node += gridDim.x) {
        const float* xr = x + (size_t)node * K;
        float acc = bias;
        #pragma unroll
        for (int j = 0; j < K; ++j) acc += xr[j] * ws[j * 256 + t];
        out[(size_t)node * 256 + t] = gelu_f(acc);
    }
}

// sage1 edge pass: message = gelu(data_x[src] @ enc_src_w^T + enc_src_b) on the fly,
// atomically accumulated into agg[dst], count into cnt[dst].
__global__ __launch_bounds__(256)
void sage1_edge(const float* __restrict__ data_x, const int* __restrict__ src,
                const int* __restrict__ dst, const float* __restrict__ w,
                const float* __restrict__ b, float* __restrict__ agg,
                float* __restrict__ cnt, int ne) {
    __shared__ float ws[8 * 256];   // transposed: ws[j][f]
    const int t = threadIdx.x;
    #pragma unroll
    for (int j = 0; j < 8; ++j) ws[j * 256 + t] = w[t * 8 + j];
    const float bias = b[t];
    __syncthreads();
    const int e0 = blockIdx.x * 128;
    const int e1 = min(e0 + 128, ne);
    for (int e = e0; e < e1; ++e) {
        const int s = src[e], d = dst[e];
        const float4 xa = *(const float4*)(data_x + (size_t)s * 8);
        const float4 xb = *(const float4*)(data_x + (size_t)s * 8 + 4);
        float acc = bias;
        acc += xa.x * ws[t]        + xa.y * ws[256 + t]  + xa.z * ws[512 + t]  + xa.w * ws[768 + t];
        acc += xb.x * ws[1024 + t] + xb.y * ws[1280 + t] + xb.z * ws[1536 + t] + xb.w * ws[1792 + t];
        atomicAdd(agg + (size_t)d * 256 + t, gelu_f(acc));
        if (t == 0) atomicAdd(cnt + d, 1.0f);
    }
}

// ranged gather edge pass: for edges with dst in [c0,c1):
//   agg[dst-c0] += feat[src] (256 feats), cnt[dst-c0] += 1
__global__ __launch_bounds__(256)
void edge_gather(const float* __restrict__ feat, const int* __restrict__ src,
                 const int* __restrict__ dst, float* __restrict__ agg,
                 float* __restrict__ cnt, int ne, int c0, int c1) {
    const int lane = threadIdx.x & 63;
    const int sub  = threadIdx.x >> 6;   // 4 edges in flight per block
    const int e0 = blockIdx.x * 64;
    const int e1 = min(e0 + 64, ne);
    for (int e = e0 + sub; e < e1; e += 4) {
        const int d = dst[e];
        if (d < c0 || d >= c1) continue;
        const int s = src[e];
        const float4 v = *(const float4*)(feat + (size_t)s * 256 + lane * 4);
        float* a = agg + (size_t)(d - c0) * 256 + lane * 4;
        atomicAdd(a + 0, v.x); atomicAdd(a + 1, v.y);
        atomicAdd(a + 2, v.z); atomicAdd(a + 3, v.w);
        if (lane == 0) atomicAdd(cnt + (d - c0), 1.0f);
    }
}

// C[M,256] = gelu( bias + (A1 * 1/max(cnt,1)) @ W1^T [+ A2 @ W2^T] )
// BM=32, BN=256. Each block reads & writes ONLY its own 32 rows -> C may alias A1 or A2.
template<int DUAL>
__global__ __launch_bounds__(256)
void node_gemm(const float* __restrict__ A1, const float* __restrict__ cnt,
               const float* __restrict__ W1,
               const float* __restrict__ A2, const float* __restrict__ W2,
               const float* __restrict__ bias, float* __restrict__ C) {
    __shared__ float As[16 * 36];    // [k][row]
    __shared__ float Bs[16 * 260];   // [k][col]
    __shared__ float s_ic[32];
    const int t = threadIdx.x;
    const int tx = t & 63, ty = t >> 6;
    const int m0 = blockIdx.x * 32;

    if (t < 32) {
        float ic = 1.0f;
        if (cnt) { float c = cnt[m0 + t]; ic = 1.0f / fmaxf(c, 1.0f); }
        s_ic[t] = ic;
    }

    float acc[8][4];
    {
        const float4 b4 = *(const float4*)(bias + tx * 4);
        #pragma unroll
        for (int im = 0; im < 8; ++im) {
            acc[im][0] = b4.x; acc[im][1] = b4.y; acc[im][2] = b4.z; acc[im][3] = b4.w;
        }
    }

    #pragma unroll
    for (int p = 0; p <= DUAL; ++p) {
        const float* Ap = p ? A2 : A1;
        const float* Wp = p ? W2 : W1;
        const bool scale = (p == 0) && (cnt != nullptr);
        for (int kt = 0; kt < 16; ++kt) {
            const int k0 = kt * 16;
            __syncthreads();
            {   // B tile: Bs[k][c] = Wp[c][k0+k], c = t
                const float* wr = Wp + (size_t)t * 256 + k0;
                #pragma unroll
                for (int q = 0; q < 4; ++q) {
                    float4 wv = *(const float4*)(wr + q * 4);
                    Bs[(q * 4 + 0) * 260 + t] = wv.x;
                    Bs[(q * 4 + 1) * 260 + t] = wv.y;
                    Bs[(q * 4 + 2) * 260 + t] = wv.z;
                    Bs[(q * 4 + 3) * 260 + t] = wv.w;
                }
            }
            if (t < 128) {   // A tile: 32 rows x 16 k
                const int r = t >> 2, kq = (t & 3) * 4;
                float4 av = *(const float4*)(Ap + (size_t)(m0 + r) * 256 + k0 + kq);
                if (scale) { const float ic = s_ic[r]; av.x *= ic; av.y *= ic; av.z *= ic; av.w *= ic; }
                As[(kq + 0) * 36 + r] = av.x;
                As[(kq + 1) * 36 + r] = av.y;
                As[(kq + 2) * 36 + r] = av.z;
                As[(kq + 3) * 36 + r] = av.w;
            }
            __syncthreads();
            #pragma unroll
            for (int kk = 0; kk < 16; ++kk) {
                const float4 a0 = *(const float4*)(&As[kk * 36 + ty * 8]);
                const float4 a1 = *(const float4*)(&As[kk * 36 + ty * 8 + 4]);
                const float4 bb = *(const float4*)(&Bs[kk * 260 + tx * 4]);
                const float am[8] = {a0.x, a0.y, a0.z, a0.w, a1.x, a1.y, a1.z, a1.w};
                const float bn[4] = {bb.x, bb.y, bb.z, bb.w};
                #pragma unroll
                for (int im = 0; im < 8; ++im)
                    #pragma unroll
                    for (int in = 0; in < 4; ++in)
                        acc[im][in] += am[im] * bn[in];
            }
        }
    }

    #pragma unroll
    for (int im = 0; im < 8; ++im) {
        float4 v;
        v.x = gelu_f(acc[im][0]); v.y = gelu_f(acc[im][1]);
        v.z = gelu_f(acc[im][2]); v.w = gelu_f(acc[im][3]);
        *(float4*)(C + (size_t)(m0 + ty * 8 + im) * 256 + tx * 4) = v;
    }
}

// out[n,8] = t_in[n,256] @ out_w[8,256]^T + out_b  (one wave per row, shuffle reduce)
__global__ __launch_bounds__(256)
void out_kernel(const float* __restrict__ tin, const float* __restrict__ ow,
                const float* __restrict__ ob, float* __restrict__ out, int n) {
    const int lane = threadIdx.x & 63;
    const int wv   = threadIdx.x >> 6;
    float owv[8][4];
    #pragma unroll
    for (int o = 0; o < 8; ++o) {
        float4 q = *(const float4*)(ow + o * 256 + lane * 4);
        owv[o][0] = q.x; owv[o][1] = q.y; owv[o][2] = q.z; owv[o][3] = q.w;
    }
    for (int row = blockIdx.x * 4 + wv; row < n; row += gridDim.x * 4) {
        const float4 v = *(const float4*)(tin + (size_t)row * 256 + lane * 4);
        float p[8];
        #pragma unroll
        for (int o = 0; o < 8; ++o)
            p[o] = v.x * owv[o][0] + v.y * owv[o][1] + v.z * owv[o][2] + v.w * owv[o][3];
        #pragma unroll
        for (int m = 1; m < 64; m <<= 1) {
            #pragma unroll
            for (int o = 0; o < 8; ++o) p[o] += __shfl_xor(p[o], m, 64);
        }
        if (lane == 0) {
            #pragma unroll
            for (int o = 0; o < 8; ++o) out[(size_t)row * 8 + o] = p[o] + ob[o];
        }
    }
}

extern "C" void kernel_launch(void* const* d_in, const int* in_sizes, int n_in,
                              void* d_out, int out_size, void* d_ws, size_t ws_size,
                              hipStream_t stream) {
    const float* data_x   = (const float*)d_in[0];
    const float* hidden_x = (const float*)d_in[1];
    const int* dh_src = (const int*)d_in[2];
    const int* dh_dst = (const int*)d_in[3];
    const int* hh_src = (const int*)d_in[4];
    const int* hh_dst = (const int*)d_in[5];
    const int* hd_src = (const int*)d_in[6];
    const int* hd_dst = (const int*)d_in[7];
    const float* enc_src_w = (const float*)d_in[8];
    const float* enc_src_b = (const float*)d_in[9];
    const float* enc_dst_w = (const float*)d_in[10];
    const float* enc_dst_b = (const float*)d_in[11];
    const float* enc_wl = (const float*)d_in[12];
    const float* enc_bl = (const float*)d_in[13];
    const float* enc_wr = (const float*)d_in[14];
    const float* proc_wl = (const float*)d_in[15];
    const float* proc_bl = (const float*)d_in[16];
    const float* proc_wr = (const float*)d_in[17];
    const float* proc_mlp_w = (const float*)d_in[18];
    const float* proc_mlp_b = (const float*)d_in[19];
    const float* dec_src_w = (const float*)d_in[20];
    const float* dec_src_b = (const float*)d_in[21];
    const float* dec_dst_w = (const float*)d_in[22];
    const float* dec_dst_b = (const float*)d_in[23];
    const float* dec_wl = (const float*)d_in[24];
    const float* dec_bl = (const float*)d_in[25];
    const float* dec_wr = (const float*)d_in[26];
    const float* out_w  = (const float*)d_in[27];
    const float* out_b  = (const float*)d_in[28];
    float* out = (float*)d_out;

    // ---- adaptive workspace layout (fp32) ----
    // fixed: h_a[NHID*256], h_b[NHID*256], cnt_h[NHID]  = 67.2 MB
    // chunked decoder: dbuf[CH*256], aggd[CH*256], cntd[CH]
    float* ws    = (float*)d_ws;
    float* h_a   = ws;
    float* h_b   = h_a + (size_t)NHID * 256;
    float* cnt_h = h_b + (size_t)NHID * 256;
    float* dbuf  = cnt_h + NHID;

    const size_t fixed_bytes = ((size_t)2 * NHID * 256 + NHID) * sizeof(float);
    size_t avail = (ws_size > fixed_bytes) ? (ws_size - fixed_bytes) : 0;
    // per-chunk bytes: CH*(2*256+1)*4 = CH*2052
    long long ch = (long long)(avail / 2052);
    ch = (ch / 2048) * 2048;                 // multiple of 2048 (divides NDATA, /32 for gemm)
    if (ch < 2048) ch = 2048;                // last-ditch floor
    if (ch > NDATA) ch = NDATA;
    const int CH = (int)ch;
    float* aggd = dbuf + (size_t)CH * 256;
    float* cntd = aggd + (size_t)CH * 256;

    // ---- encoder ----
    enc_kernel<3><<<512, 256, 0, stream>>>(hidden_x, enc_dst_w, enc_dst_b, h_a, NHID);
    hipMemsetAsync(h_b, 0, (size_t)NHID * 256 * sizeof(float), stream);
    hipMemsetAsync(cnt_h, 0, (size_t)NHID * sizeof(float), stream);
    sage1_edge<<<NEDGE / 128, 256, 0, stream>>>(data_x, dh_src, dh_dst, enc_src_w, enc_src_b, h_b, cnt_h, NEDGE);
    // H1 = gelu(mean@enc_wl^T + enc_bl + h_a@enc_wr^T)  -> write over h_b (aliases A1, safe per-block)
    node_gemm<1><<<NHID / 32, 256, 0, stream>>>(h_b, cnt_h, enc_wl, h_a, enc_wr, enc_bl, h_b);

    // ---- processor ----
    hipMemsetAsync(h_a, 0, (size_t)NHID * 256 * sizeof(float), stream);
    hipMemsetAsync(cnt_h, 0, (size_t)NHID * sizeof(float), stream);
    edge_gather<<<NEDGE / 64, 256, 0, stream>>>(h_b, hh_src, hh_dst, h_a, cnt_h, NEDGE, 0, NHID);
    // store gelu(H2) (downstream only uses gelu(H2)) -> over h_a
    node_gemm<1><<<NHID / 32, 256, 0, stream>>>(h_a, cnt_h, proc_wl, h_b, proc_wr, proc_bl, h_a);
    // H3 = gelu(gelu(H2)@mlp_w^T + mlp_b) -> h_b
    node_gemm<0><<<NHID / 32, 256, 0, stream>>>(h_a, nullptr, proc_mlp_w, nullptr, nullptr, proc_mlp_b, h_b);
    // s = gelu(H3@dec_src_w^T + dec_src_b) -> h_a
    node_gemm<0><<<NHID / 32, 256, 0, stream>>>(h_b, nullptr, dec_src_w, nullptr, nullptr, dec_src_b, h_a);

    // ---- decoder (chunked over data nodes) ----
    for (int c0 = 0; c0 < NDATA; c0 += CH) {
        const int cc = min(CH, NDATA - c0);
        enc_kernel<8><<<2048, 256, 0, stream>>>(data_x + (size_t)c0 * 8, dec_dst_w, dec_dst_b, dbuf, cc);
        hipMemsetAsync(aggd, 0, (size_t)cc * 256 * sizeof(float), stream);
        hipMemsetAsync(cntd, 0, (size_t)cc * sizeof(float), stream);
        edge_gather<<<NEDGE / 64, 256, 0, stream>>>(h_a, hd_src, hd_dst, aggd, cntd, NEDGE, c0, c0 + cc);
        // t = gelu(mean@dec_wl^T + dec_bl + dbuf@dec_wr^T) -> in place over dbuf
        node_gemm<1><<<cc / 32, 256, 0, stream>>>(aggd, cntd, dec_wl, dbuf, dec_wr, dec_bl, dbuf);
        out_kernel<<<4096, 256, 0, stream>>>(dbuf, out_w, out_b, out + (size_t)c0 * 8, cc);
    }
}

// Round 3
// 1962.364 us; speedup vs baseline: 2.6344x; 2.6344x over previous
//
#include <hip/hip_runtime.h>

#define NDATA 131072
#define NHID  32768
#define NEDGE 524288

__device__ __forceinline__ float gelu_f(float x) {
    return 0.5f * x * (1.0f + erff(x * 0.7071067811865476f));
}

// ---------------- CSR build ----------------

__global__ __launch_bounds__(256)
void hist_kernel(const int* __restrict__ dst, int* __restrict__ cnt, int ne) {
    const int i = blockIdx.x * 256 + threadIdx.x;
    if (i < ne) atomicAdd(&cnt[dst[i]], 1);
}

// single-block exclusive scan over n bins (n <= 131072). cnt may alias cursor.
__global__ __launch_bounds__(1024)
void scan_kernel(const int* __restrict__ cnt, int* __restrict__ row_ptr,
                 int* __restrict__ cursor, int n) {
    __shared__ int part[1024];
    const int t = threadIdx.x;
    const int per = (n + 1023) >> 10;
    const int base = t * per;
    int s = 0;
    for (int i = 0; i < per && base + i < n; ++i) s += cnt[base + i];
    part[t] = s;
    __syncthreads();
    for (int off = 1; off < 1024; off <<= 1) {
        int v = 0;
        if (t >= off) v = part[t - off];
        __syncthreads();
        if (t >= off) part[t] += v;
        __syncthreads();
    }
    int excl = (t == 0) ? 0 : part[t - 1];
    for (int i = 0; i < per && base + i < n; ++i) {
        const int c = cnt[base + i];          // read BEFORE overwriting (alias-safe)
        row_ptr[base + i] = excl;
        cursor[base + i]  = excl;
        excl += c;
    }
    if (t == 1023) row_ptr[n] = excl;
}

__global__ __launch_bounds__(256)
void scatter_kernel(const int* __restrict__ src, const int* __restrict__ dst,
                    int* __restrict__ cursor, int* __restrict__ sorted_src, int ne) {
    const int i = blockIdx.x * 256 + threadIdx.x;
    if (i < ne) {
        const int p = atomicAdd(&cursor[dst[i]], 1);
        sorted_src[p] = src[i];
    }
}

// ---------------- CSR aggregation (mean) ----------------

// one wave per dst node; lane owns 4 features; mean written pre-divided
__global__ __launch_bounds__(256)
void csr_gather_mean(const float* __restrict__ feat, const int* __restrict__ row_ptr,
                     const int* __restrict__ sorted_src, float* __restrict__ mean, int n) {
    const int lane = threadIdx.x & 63;
    const int w = blockIdx.x * 4 + (threadIdx.x >> 6);
    if (w >= n) return;
    const int e0 = row_ptr[w], e1 = row_ptr[w + 1];
    float4 acc = {0.f, 0.f, 0.f, 0.f};
    int e = e0;
    for (; e + 1 < e1; e += 2) {
        const int s0 = sorted_src[e], s1 = sorted_src[e + 1];
        const float4 v0 = *(const float4*)(feat + (size_t)s0 * 256 + lane * 4);
        const float4 v1 = *(const float4*)(feat + (size_t)s1 * 256 + lane * 4);
        acc.x += v0.x + v1.x; acc.y += v0.y + v1.y;
        acc.z += v0.z + v1.z; acc.w += v0.w + v1.w;
    }
    if (e < e1) {
        const int s0 = sorted_src[e];
        const float4 v0 = *(const float4*)(feat + (size_t)s0 * 256 + lane * 4);
        acc.x += v0.x; acc.y += v0.y; acc.z += v0.z; acc.w += v0.w;
    }
    const float ic = 1.0f / fmaxf((float)(e1 - e0), 1.0f);
    acc.x *= ic; acc.y *= ic; acc.z *= ic; acc.w *= ic;
    *(float4*)(mean + (size_t)w * 256 + lane * 4) = acc;
}

// sage1: message = gelu(data_x[src] @ enc_src_w^T + enc_src_b) computed on the fly
__global__ __launch_bounds__(256)
void csr_sage1_mean(const float* __restrict__ data_x, const int* __restrict__ row_ptr,
                    const int* __restrict__ sorted_src, const float* __restrict__ w,
                    const float* __restrict__ b, float* __restrict__ mean, int n) {
    const int lane = threadIdx.x & 63;
    float wr[4][8], bias[4];
    #pragma unroll
    for (int r = 0; r < 4; ++r) {
        #pragma unroll
        for (int j = 0; j < 8; ++j) wr[r][j] = w[(lane * 4 + r) * 8 + j];
        bias[r] = b[lane * 4 + r];
    }
    const int wv = blockIdx.x * 4 + (threadIdx.x >> 6);
    if (wv >= n) return;
    const int e0 = row_ptr[wv], e1 = row_ptr[wv + 1];
    float4 acc = {0.f, 0.f, 0.f, 0.f};
    for (int e = e0; e < e1; ++e) {
        const int s = sorted_src[e];
        const float4 xa = *(const float4*)(data_x + (size_t)s * 8);
        const float4 xb = *(const float4*)(data_x + (size_t)s * 8 + 4);
        float m[4];
        #pragma unroll
        for (int r = 0; r < 4; ++r)
            m[r] = bias[r] + xa.x * wr[r][0] + xa.y * wr[r][1] + xa.z * wr[r][2] + xa.w * wr[r][3]
                           + xb.x * wr[r][4] + xb.y * wr[r][5] + xb.z * wr[r][6] + xb.w * wr[r][7];
        acc.x += gelu_f(m[0]); acc.y += gelu_f(m[1]);
        acc.z += gelu_f(m[2]); acc.w += gelu_f(m[3]);
    }
    const float ic = 1.0f / fmaxf((float)(e1 - e0), 1.0f);
    acc.x *= ic; acc.y *= ic; acc.z *= ic; acc.w *= ic;
    *(float4*)(mean + (size_t)wv * 256 + lane * 4) = acc;
}

// ---------------- dense kernels ----------------

// out[n,256] = gelu(x[n,K] @ w[256,K]^T + b)
template<int K>
__global__ __launch_bounds__(256)
void enc_kernel(const float* __restrict__ x, const float* __restrict__ w,
                const float* __restrict__ b, float* __restrict__ out, int n) {
    __shared__ float ws[K * 256];
    const int t = threadIdx.x;
    #pragma unroll
    for (int j = 0; j < K; ++j) ws[j * 256 + t] = w[t * K + j];
    const float bias = b[t];
    __syncthreads();
    for (int node = blockIdx.x; node < n; node += gridDim.x) {
        const float* xr = x + (size_t)node * K;
        float acc = bias;
        #pragma unroll
        for (int j = 0; j < K; ++j) acc += xr[j] * ws[j * 256 + t];
        out[(size_t)node * 256 + t] = gelu_f(acc);
    }
}

// C[M,256] = gelu( bias + A1 @ W1^T [+ A2 @ W2^T] ), BM=32, BN=256.
// Each block touches only its own 32 rows -> C may alias A1 or A2.
template<int DUAL>
__global__ __launch_bounds__(256)
void node_gemm(const float* __restrict__ A1, const float* __restrict__ W1,
               const float* __restrict__ A2, const float* __restrict__ W2,
               const float* __restrict__ bias, float* __restrict__ C) {
    __shared__ float As[16 * 36];
    __shared__ float Bs[16 * 260];
    const int t = threadIdx.x;
    const int tx = t & 63, ty = t >> 6;
    const int m0 = blockIdx.x * 32;

    float acc[8][4];
    {
        const float4 b4 = *(const float4*)(bias + tx * 4);
        #pragma unroll
        for (int im = 0; im < 8; ++im) {
            acc[im][0] = b4.x; acc[im][1] = b4.y; acc[im][2] = b4.z; acc[im][3] = b4.w;
        }
    }

    #pragma unroll
    for (int p = 0; p <= DUAL; ++p) {
        const float* Ap = p ? A2 : A1;
        const float* Wp = p ? W2 : W1;
        for (int kt = 0; kt < 16; ++kt) {
            const int k0 = kt * 16;
            __syncthreads();
            {
                const float* wrp = Wp + (size_t)t * 256 + k0;
                #pragma unroll
                for (int q = 0; q < 4; ++q) {
                    float4 wv = *(const float4*)(wrp + q * 4);
                    Bs[(q * 4 + 0) * 260 + t] = wv.x;
                    Bs[(q * 4 + 1) * 260 + t] = wv.y;
                    Bs[(q * 4 + 2) * 260 + t] = wv.z;
                    Bs[(q * 4 + 3) * 260 + t] = wv.w;
                }
            }
            if (t < 128) {
                const int r = t >> 2, kq = (t & 3) * 4;
                float4 av = *(const float4*)(Ap + (size_t)(m0 + r) * 256 + k0 + kq);
                As[(kq + 0) * 36 + r] = av.x;
                As[(kq + 1) * 36 + r] = av.y;
                As[(kq + 2) * 36 + r] = av.z;
                As[(kq + 3) * 36 + r] = av.w;
            }
            __syncthreads();
            #pragma unroll
            for (int kk = 0; kk < 16; ++kk) {
                const float4 a0 = *(const float4*)(&As[kk * 36 + ty * 8]);
                const float4 a1 = *(const float4*)(&As[kk * 36 + ty * 8 + 4]);
                const float4 bb = *(const float4*)(&Bs[kk * 260 + tx * 4]);
                const float am[8] = {a0.x, a0.y, a0.z, a0.w, a1.x, a1.y, a1.z, a1.w};
                const float bn[4] = {bb.x, bb.y, bb.z, bb.w};
                #pragma unroll
                for (int im = 0; im < 8; ++im)
                    #pragma unroll
                    for (int in = 0; in < 4; ++in)
                        acc[im][in] += am[im] * bn[in];
            }
        }
    }

    #pragma unroll
    for (int im = 0; im < 8; ++im) {
        float4 v;
        v.x = gelu_f(acc[im][0]); v.y = gelu_f(acc[im][1]);
        v.z = gelu_f(acc[im][2]); v.w = gelu_f(acc[im][3]);
        *(float4*)(C + (size_t)(m0 + ty * 8 + im) * 256 + tx * 4) = v;
    }
}

// Decoder fused: t = gelu(dec_bl + mean3@dec_wl^T + d@dec_wr^T),
// d = gelu(data_x@dec_dst_w^T + dec_dst_b) computed on the fly,
// out = t @ out_w^T + out_b  (wave shuffle-reduce epilogue).
__global__ __launch_bounds__(256)
void dec_gemm(const float* __restrict__ A1, const float* __restrict__ W1,
              const float* __restrict__ xdat, const float* __restrict__ Wd,
              const float* __restrict__ bd, const float* __restrict__ W2,
              const float* __restrict__ bias, const float* __restrict__ ow,
              const float* __restrict__ ob, float* __restrict__ out) {
    __shared__ float As[16 * 36];
    __shared__ float Bs[16 * 260];
    __shared__ float xs[32 * 8];
    __shared__ float wds[256 * 8];
    __shared__ float bds[256];
    const int t = threadIdx.x;
    const int tx = t & 63, ty = t >> 6;
    const int m0 = blockIdx.x * 32;

    xs[t] = xdat[(size_t)m0 * 8 + t];
    #pragma unroll
    for (int j = 0; j < 8; ++j) wds[t * 8 + j] = Wd[t * 8 + j];
    bds[t] = bd[t];

    float ow_reg[8][4], ob_reg[8];
    #pragma unroll
    for (int o = 0; o < 8; ++o) {
        float4 q = *(const float4*)(ow + o * 256 + tx * 4);
        ow_reg[o][0] = q.x; ow_reg[o][1] = q.y; ow_reg[o][2] = q.z; ow_reg[o][3] = q.w;
        ob_reg[o] = ob[o];
    }

    float acc[8][4];
    {
        const float4 b4 = *(const float4*)(bias + tx * 4);
        #pragma unroll
        for (int im = 0; im < 8; ++im) {
            acc[im][0] = b4.x; acc[im][1] = b4.y; acc[im][2] = b4.z; acc[im][3] = b4.w;
        }
    }

    #pragma unroll
    for (int p = 0; p < 2; ++p) {
        const float* Wp = p ? W2 : W1;
        for (int kt = 0; kt < 16; ++kt) {
            const int k0 = kt * 16;
            __syncthreads();
            {
                const float* wrp = Wp + (size_t)t * 256 + k0;
                #pragma unroll
                for (int q = 0; q < 4; ++q) {
                    float4 wv = *(const float4*)(wrp + q * 4);
                    Bs[(q * 4 + 0) * 260 + t] = wv.x;
                    Bs[(q * 4 + 1) * 260 + t] = wv.y;
                    Bs[(q * 4 + 2) * 260 + t] = wv.z;
                    Bs[(q * 4 + 3) * 260 + t] = wv.w;
                }
            }
            if (t < 128) {
                const int r = t >> 2, kq = (t & 3) * 4;
                if (p == 0) {
                    float4 av = *(const float4*)(A1 + (size_t)(m0 + r) * 256 + k0 + kq);
                    As[(kq + 0) * 36 + r] = av.x;
                    As[(kq + 1) * 36 + r] = av.y;
                    As[(kq + 2) * 36 + r] = av.z;
                    As[(kq + 3) * 36 + r] = av.w;
                } else {
                    #pragma unroll
                    for (int q = 0; q < 4; ++q) {
                        const int k = k0 + kq + q;
                        float val = bds[k];
                        #pragma unroll
                        for (int j = 0; j < 8; ++j) val += xs[r * 8 + j] * wds[k * 8 + j];
                        As[(kq + q) * 36 + r] = gelu_f(val);
                    }
                }
            }
            __syncthreads();
            #pragma unroll
            for (int kk = 0; kk < 16; ++kk) {
                const float4 a0 = *(const float4*)(&As[kk * 36 + ty * 8]);
                const float4 a1 = *(const float4*)(&As[kk * 36 + ty * 8 + 4]);
                const float4 bb = *(const float4*)(&Bs[kk * 260 + tx * 4]);
                const float am[8] = {a0.x, a0.y, a0.z, a0.w, a1.x, a1.y, a1.z, a1.w};
                const float bn[4] = {bb.x, bb.y, bb.z, bb.w};
                #pragma unroll
                for (int im = 0; im < 8; ++im)
                    #pragma unroll
                    for (int in = 0; in < 4; ++in)
                        acc[im][in] += am[im] * bn[in];
            }
        }
    }

    // fused 256->8 projection: wave (fixed ty, tx=0..63) covers all 256 cols of rows ty*8..ty*8+7
    #pragma unroll
    for (int g = 0; g < 2; ++g) {
        float p[4][8];
        #pragma unroll
        for (int i4 = 0; i4 < 4; ++i4) {
            const int im = g * 4 + i4;
            float tv[4];
            #pragma unroll
            for (int in = 0; in < 4; ++in) tv[in] = gelu_f(acc[im][in]);
            #pragma unroll
            for (int o = 0; o < 8; ++o)
                p[i4][o] = tv[0] * ow_reg[o][0] + tv[1] * ow_reg[o][1]
                         + tv[2] * ow_reg[o][2] + tv[3] * ow_reg[o][3];
        }
        #pragma unroll
        for (int m = 1; m < 64; m <<= 1)
            #pragma unroll
            for (int i4 = 0; i4 < 4; ++i4)
                #pragma unroll
                for (int o = 0; o < 8; ++o)
                    p[i4][o] += __shfl_xor(p[i4][o], m, 64);
        if (tx == 0) {
            #pragma unroll
            for (int i4 = 0; i4 < 4; ++i4) {
                const int row = m0 + ty * 8 + g * 4 + i4;
                float4 lo = {p[i4][0] + ob_reg[0], p[i4][1] + ob_reg[1],
                             p[i4][2] + ob_reg[2], p[i4][3] + ob_reg[3]};
                float4 hi = {p[i4][4] + ob_reg[4], p[i4][5] + ob_reg[5],
                             p[i4][6] + ob_reg[6], p[i4][7] + ob_reg[7]};
                *(float4*)(out + (size_t)row * 8)     = lo;
                *(float4*)(out + (size_t)row * 8 + 4) = hi;
            }
        }
    }
}

// ---------------- launch ----------------

static void build_csr(const int* src, const int* dst, int n, int ne,
                      int* cursor, int* row_ptr, int* sorted_src, hipStream_t stream) {
    hipMemsetAsync(cursor, 0, (size_t)n * sizeof(int), stream);
    hist_kernel<<<(ne + 255) / 256, 256, 0, stream>>>(dst, cursor, ne);
    scan_kernel<<<1, 1024, 0, stream>>>(cursor, row_ptr, cursor, n);
    scatter_kernel<<<(ne + 255) / 256, 256, 0, stream>>>(src, dst, cursor, sorted_src, ne);
}

extern "C" void kernel_launch(void* const* d_in, const int* in_sizes, int n_in,
                              void* d_out, int out_size, void* d_ws, size_t ws_size,
                              hipStream_t stream) {
    const float* data_x   = (const float*)d_in[0];
    const float* hidden_x = (const float*)d_in[1];
    const int* dh_src = (const int*)d_in[2];
    const int* dh_dst = (const int*)d_in[3];
    const int* hh_src = (const int*)d_in[4];
    const int* hh_dst = (const int*)d_in[5];
    const int* hd_src = (const int*)d_in[6];
    const int* hd_dst = (const int*)d_in[7];
    const float* enc_src_w = (const float*)d_in[8];
    const float* enc_src_b = (const float*)d_in[9];
    const float* enc_dst_w = (const float*)d_in[10];
    const float* enc_dst_b = (const float*)d_in[11];
    const float* enc_wl = (const float*)d_in[12];
    const float* enc_bl = (const float*)d_in[13];
    const float* enc_wr = (const float*)d_in[14];
    const float* proc_wl = (const float*)d_in[15];
    const float* proc_bl = (const float*)d_in[16];
    const float* proc_wr = (const float*)d_in[17];
    const float* proc_mlp_w = (const float*)d_in[18];
    const float* proc_mlp_b = (const float*)d_in[19];
    const float* dec_src_w = (const float*)d_in[20];
    const float* dec_src_b = (const float*)d_in[21];
    const float* dec_dst_w = (const float*)d_in[22];
    const float* dec_dst_b = (const float*)d_in[23];
    const float* dec_wl = (const float*)d_in[24];
    const float* dec_bl = (const float*)d_in[25];
    const float* dec_wr = (const float*)d_in[26];
    const float* out_w  = (const float*)d_in[27];
    const float* out_b  = (const float*)d_in[28];
    float* out = (float*)d_out;

    // workspace: h_a, h_b [NHID*256], aggd [NDATA*256], CSR ints  (~205 MB)
    float* ws   = (float*)d_ws;
    float* h_a  = ws;
    float* h_b  = h_a + (size_t)NHID * 256;
    float* aggd = h_b + (size_t)NHID * 256;
    int* row_ptr    = (int*)(aggd + (size_t)NDATA * 256);
    int* cursor     = row_ptr + (NDATA + 1);
    int* sorted_src = cursor + NDATA;

    // ---- encoder ----
    enc_kernel<3><<<512, 256, 0, stream>>>(hidden_x, enc_dst_w, enc_dst_b, h_a, NHID);
    build_csr(dh_src, dh_dst, NHID, NEDGE, cursor, row_ptr, sorted_src, stream);
    csr_sage1_mean<<<NHID / 4, 256, 0, stream>>>(data_x, row_ptr, sorted_src,
                                                 enc_src_w, enc_src_b, h_b, NHID);
    // H1 = gelu(mean1@enc_wl^T + enc_bl + h_a@enc_wr^T) -> h_b (in-place over A1)
    node_gemm<1><<<NHID / 32, 256, 0, stream>>>(h_b, enc_wl, h_a, enc_wr, enc_bl, h_b);

    // ---- processor ----
    build_csr(hh_src, hh_dst, NHID, NEDGE, cursor, row_ptr, sorted_src, stream);
    csr_gather_mean<<<NHID / 4, 256, 0, stream>>>(h_b, row_ptr, sorted_src, h_a, NHID);
    // gelu(H2) -> h_a (in-place over A1=mean2)
    node_gemm<1><<<NHID / 32, 256, 0, stream>>>(h_a, proc_wl, h_b, proc_wr, proc_bl, h_a);
    // H3 = gelu(gelu(H2)@mlp_w^T + mlp_b) -> h_b
    node_gemm<0><<<NHID / 32, 256, 0, stream>>>(h_a, proc_mlp_w, nullptr, nullptr, proc_mlp_b, h_b);
    // s = gelu(H3@dec_src_w^T + dec_src_b) -> h_a
    node_gemm<0><<<NHID / 32, 256, 0, stream>>>(h_b, dec_src_w, nullptr, nullptr, dec_src_b, h_a);

    // ---- decoder ----
    build_csr(hd_src, hd_dst, NDATA, NEDGE, cursor, row_ptr, sorted_src, stream);
    csr_gather_mean<<<NDATA / 4, 256, 0, stream>>>(h_a, row_ptr, sorted_src, aggd, NDATA);
    dec_gemm<<<NDATA / 32, 256, 0, stream>>>(aggd, dec_wl, data_x, dec_dst_w, dec_dst_b,
                                             dec_wr, dec_bl, out_w, out_b, out);
}

// Round 4
// 1145.526 us; speedup vs baseline: 4.5128x; 1.7131x over previous
//
#include <hip/hip_runtime.h>

#define NDATA 131072
#define NHID  32768
#define NEDGE 524288

typedef __bf16 bf16_t;
typedef __bf16 bf16x4 __attribute__((ext_vector_type(4)));
typedef __bf16 bf16x8 __attribute__((ext_vector_type(8)));
typedef float  f32x4  __attribute__((ext_vector_type(4)));

__device__ __forceinline__ float gelu_f(float x) {
    return 0.5f * x * (1.0f + erff(x * 0.7071067811865476f));
}

// ---------------- weight fp32 -> bf16 conversion ----------------
struct WPtrs { const float* p[8]; };

__global__ __launch_bounds__(256)
void cvt_w_kernel(WPtrs wp, bf16_t* __restrict__ out) {
    const int i = blockIdx.x * 256 + threadIdx.x;   // 8 * 65536 total
    const int wsel = i >> 16, off = i & 65535;
    out[i] = (bf16_t)wp.p[wsel][off];
}

// ---------------- CSR build ----------------

__global__ __launch_bounds__(256)
void hist_kernel(const int* __restrict__ dst, int* __restrict__ cnt, int ne) {
    const int i = blockIdx.x * 256 + threadIdx.x;
    if (i < ne) atomicAdd(&cnt[dst[i]], 1);
}

// single-block exclusive scan over n bins. cnt may alias cursor.
__global__ __launch_bounds__(1024)
void scan_kernel(const int* __restrict__ cnt, int* __restrict__ row_ptr,
                 int* __restrict__ cursor, int n) {
    __shared__ int part[1024];
    const int t = threadIdx.x;
    const int per = (n + 1023) >> 10;
    const int base = t * per;
    int s = 0;
    for (int i = 0; i < per && base + i < n; ++i) s += cnt[base + i];
    part[t] = s;
    __syncthreads();
    for (int off = 1; off < 1024; off <<= 1) {
        int v = 0;
        if (t >= off) v = part[t - off];
        __syncthreads();
        if (t >= off) part[t] += v;
        __syncthreads();
    }
    int excl = (t == 0) ? 0 : part[t - 1];
    for (int i = 0; i < per && base + i < n; ++i) {
        const int c = cnt[base + i];
        row_ptr[base + i] = excl;
        cursor[base + i]  = excl;
        excl += c;
    }
    if (t == 1023) row_ptr[n] = excl;
}

__global__ __launch_bounds__(256)
void scatter_kernel(const int* __restrict__ src, const int* __restrict__ dst,
                    int* __restrict__ cursor, int* __restrict__ sorted_src, int ne) {
    const int i = blockIdx.x * 256 + threadIdx.x;
    if (i < ne) {
        const int p = atomicAdd(&cursor[dst[i]], 1);
        sorted_src[p] = src[i];
    }
}

// ---------------- CSR aggregation (mean), bf16 features ----------------

__global__ __launch_bounds__(256)
void csr_gather_mean(const bf16_t* __restrict__ feat, const int* __restrict__ row_ptr,
                     const int* __restrict__ sorted_src, bf16_t* __restrict__ mean, int n) {
    const int lane = threadIdx.x & 63;
    const int w = blockIdx.x * 4 + (threadIdx.x >> 6);
    if (w >= n) return;
    const int e0 = row_ptr[w], e1 = row_ptr[w + 1];
    float ax = 0.f, ay = 0.f, az = 0.f, aw = 0.f;
    int e = e0;
    for (; e + 1 < e1; e += 2) {
        const int s0 = sorted_src[e], s1 = sorted_src[e + 1];
        const bf16x4 v0 = *(const bf16x4*)(feat + (size_t)s0 * 256 + lane * 4);
        const bf16x4 v1 = *(const bf16x4*)(feat + (size_t)s1 * 256 + lane * 4);
        ax += (float)v0[0] + (float)v1[0]; ay += (float)v0[1] + (float)v1[1];
        az += (float)v0[2] + (float)v1[2]; aw += (float)v0[3] + (float)v1[3];
    }
    if (e < e1) {
        const int s0 = sorted_src[e];
        const bf16x4 v0 = *(const bf16x4*)(feat + (size_t)s0 * 256 + lane * 4);
        ax += (float)v0[0]; ay += (float)v0[1]; az += (float)v0[2]; aw += (float)v0[3];
    }
    const float ic = 1.0f / fmaxf((float)(e1 - e0), 1.0f);
    bf16x4 r;
    r[0] = (bf16_t)(ax * ic); r[1] = (bf16_t)(ay * ic);
    r[2] = (bf16_t)(az * ic); r[3] = (bf16_t)(aw * ic);
    *(bf16x4*)(mean + (size_t)w * 256 + lane * 4) = r;
}

// sage1: message = gelu(data_x[src] @ enc_src_w^T + enc_src_b) computed on the fly (fp32 math)
__global__ __launch_bounds__(256)
void csr_sage1_mean(const float* __restrict__ data_x, const int* __restrict__ row_ptr,
                    const int* __restrict__ sorted_src, const float* __restrict__ w,
                    const float* __restrict__ b, bf16_t* __restrict__ mean, int n) {
    const int lane = threadIdx.x & 63;
    float wr[4][8], bias[4];
    #pragma unroll
    for (int r = 0; r < 4; ++r) {
        #pragma unroll
        for (int j = 0; j < 8; ++j) wr[r][j] = w[(lane * 4 + r) * 8 + j];
        bias[r] = b[lane * 4 + r];
    }
    const int wv = blockIdx.x * 4 + (threadIdx.x >> 6);
    if (wv >= n) return;
    const int e0 = row_ptr[wv], e1 = row_ptr[wv + 1];
    float acc[4] = {0.f, 0.f, 0.f, 0.f};
    for (int e = e0; e < e1; ++e) {
        const int s = sorted_src[e];
        const float4 xa = *(const float4*)(data_x + (size_t)s * 8);
        const float4 xb = *(const float4*)(data_x + (size_t)s * 8 + 4);
        #pragma unroll
        for (int r = 0; r < 4; ++r) {
            float m = bias[r] + xa.x * wr[r][0] + xa.y * wr[r][1] + xa.z * wr[r][2] + xa.w * wr[r][3]
                              + xb.x * wr[r][4] + xb.y * wr[r][5] + xb.z * wr[r][6] + xb.w * wr[r][7];
            acc[r] += gelu_f(m);
        }
    }
    const float ic = 1.0f / fmaxf((float)(e1 - e0), 1.0f);
    bf16x4 r4;
    #pragma unroll
    for (int r = 0; r < 4; ++r) r4[r] = (bf16_t)(acc[r] * ic);
    *(bf16x4*)(mean + (size_t)wv * 256 + lane * 4) = r4;
}

// ---------------- small-K encoder (fp32 math, bf16 out) ----------------
template<int K>
__global__ __launch_bounds__(256)
void enc_kernel(const float* __restrict__ x, const float* __restrict__ w,
                const float* __restrict__ b, bf16_t* __restrict__ out, int n) {
    __shared__ float ws[K * 256];
    const int t = threadIdx.x;
    #pragma unroll
    for (int j = 0; j < K; ++j) ws[j * 256 + t] = w[t * K + j];
    const float bias = b[t];
    __syncthreads();
    for (int node = blockIdx.x; node < n; node += gridDim.x) {
        const float* xr = x + (size_t)node * K;
        float acc = bias;
        #pragma unroll
        for (int j = 0; j < K; ++j) acc += xr[j] * ws[j * 256 + t];
        out[(size_t)node * 256 + t] = (bf16_t)gelu_f(acc);
    }
}

// ---------------- MFMA bf16 GEMM ----------------
// C[M,256] = gelu( bias + A1 @ W1^T [+ A2 @ W2^T] )
// A row-major [M][256] bf16, W row-major [256][256] bf16 ([n][k] == B^T fragment layout).
// BM=64, BN=256 (full width), BK=32; 4 waves, wave w owns cols [w*64, w*64+64).
// Blocks touch only their own 64 rows -> C may alias A1 or A2.
#define ASTR 40   // LDS row stride in bf16 (32 + 8 pad = 80 B): b128 ops tile all 32 banks
template<int DUAL>
__global__ __launch_bounds__(256)
void mfma_gemm(const bf16_t* __restrict__ A1, const bf16_t* __restrict__ W1,
               const bf16_t* __restrict__ A2, const bf16_t* __restrict__ W2,
               const float* __restrict__ bias, bf16_t* __restrict__ C) {
    __shared__ bf16_t As[64 * ASTR];    // 5 KB
    __shared__ bf16_t Bs[256 * ASTR];   // 20 KB
    const int t = threadIdx.x;
    const int w = t >> 6, lane = t & 63;
    const int l15 = lane & 15, l4 = lane >> 4;
    const int m0 = blockIdx.x * 64;

    f32x4 acc[4][4];
    #pragma unroll
    for (int nb = 0; nb < 4; ++nb) {
        const float bv = bias[w * 64 + nb * 16 + l15];
        #pragma unroll
        for (int m = 0; m < 4; ++m) {
            acc[m][nb][0] = bv; acc[m][nb][1] = bv; acc[m][nb][2] = bv; acc[m][nb][3] = bv;
        }
    }

    const int ar = t >> 2, aq = t & 3;      // A staging: row, 8-elem quarter
    #pragma unroll
    for (int p = 0; p <= DUAL; ++p) {
        const bf16_t* Ap = p ? A2 : A1;
        const bf16_t* Wp = p ? W2 : W1;
        for (int kt = 0; kt < 8; ++kt) {
            const int k0 = kt * 32;
            __syncthreads();
            // stage A: 64 rows x 32 k
            *(bf16x8*)(&As[ar * ASTR + aq * 8]) =
                *(const bf16x8*)(Ap + (size_t)(m0 + ar) * 256 + k0 + aq * 8);
            // stage B: 256 n-rows x 32 k
            {
                const bf16_t* wrp = Wp + (size_t)t * 256 + k0;
                #pragma unroll
                for (int q = 0; q < 4; ++q)
                    *(bf16x8*)(&Bs[t * ASTR + q * 8]) = *(const bf16x8*)(wrp + q * 8);
            }
            __syncthreads();
            // fragments: A lane row=l15, k=(l4)*8+j ; B lane col=l15, k=(l4)*8+j
            bf16x8 af[4], bfr[4];
            #pragma unroll
            for (int m = 0; m < 4; ++m)
                af[m] = *(const bf16x8*)(&As[(m * 16 + l15) * ASTR + l4 * 8]);
            #pragma unroll
            for (int nb = 0; nb < 4; ++nb)
                bfr[nb] = *(const bf16x8*)(&Bs[(w * 64 + nb * 16 + l15) * ASTR + l4 * 8]);
            #pragma unroll
            for (int m = 0; m < 4; ++m)
                #pragma unroll
                for (int nb = 0; nb < 4; ++nb)
                    acc[m][nb] = __builtin_amdgcn_mfma_f32_16x16x32_bf16(af[m], bfr[nb], acc[m][nb], 0, 0, 0);
        }
    }

    // epilogue: C/D layout col=lane&15, row=(lane>>4)*4+i
    #pragma unroll
    for (int m = 0; m < 4; ++m) {
        #pragma unroll
        for (int nb = 0; nb < 4; ++nb) {
            const int col = w * 64 + nb * 16 + l15;
            #pragma unroll
            for (int i = 0; i < 4; ++i) {
                const int row = m0 + m * 16 + l4 * 4 + i;
                C[(size_t)row * 256 + col] = (bf16_t)gelu_f(acc[m][nb][i]);
            }
        }
    }
}

// out[n,8] = t_in[n,256](bf16) @ out_w[8,256]^T + out_b
__global__ __launch_bounds__(256)
void out_kernel(const bf16_t* __restrict__ tin, const float* __restrict__ ow,
                const float* __restrict__ ob, float* __restrict__ out, int n) {
    const int lane = threadIdx.x & 63;
    const int wv   = threadIdx.x >> 6;
    float owv[8][4];
    #pragma unroll
    for (int o = 0; o < 8; ++o) {
        float4 q = *(const float4*)(ow + o * 256 + lane * 4);
        owv[o][0] = q.x; owv[o][1] = q.y; owv[o][2] = q.z; owv[o][3] = q.w;
    }
    for (int row = blockIdx.x * 4 + wv; row < n; row += gridDim.x * 4) {
        const bf16x4 v = *(const bf16x4*)(tin + (size_t)row * 256 + lane * 4);
        const float v0 = (float)v[0], v1 = (float)v[1], v2 = (float)v[2], v3 = (float)v[3];
        float p[8];
        #pragma unroll
        for (int o = 0; o < 8; ++o)
            p[o] = v0 * owv[o][0] + v1 * owv[o][1] + v2 * owv[o][2] + v3 * owv[o][3];
        #pragma unroll
        for (int m = 1; m < 64; m <<= 1) {
            #pragma unroll
            for (int o = 0; o < 8; ++o) p[o] += __shfl_xor(p[o], m, 64);
        }
        if (lane == 0) {
            #pragma unroll
            for (int o = 0; o < 8; ++o) out[(size_t)row * 8 + o] = p[o] + ob[o];
        }
    }
}

// ---------------- launch ----------------

static void build_csr(const int* src, const int* dst, int n, int ne,
                      int* cursor, int* row_ptr, int* sorted_src, hipStream_t stream) {
    hipMemsetAsync(cursor, 0, (size_t)n * sizeof(int), stream);
    hist_kernel<<<(ne + 255) / 256, 256, 0, stream>>>(dst, cursor, ne);
    scan_kernel<<<1, 1024, 0, stream>>>(cursor, row_ptr, cursor, n);
    scatter_kernel<<<(ne + 255) / 256, 256, 0, stream>>>(src, dst, cursor, sorted_src, ne);
}

extern "C" void kernel_launch(void* const* d_in, const int* in_sizes, int n_in,
                              void* d_out, int out_size, void* d_ws, size_t ws_size,
                              hipStream_t stream) {
    const float* data_x   = (const float*)d_in[0];
    const float* hidden_x = (const float*)d_in[1];
    const int* dh_src = (const int*)d_in[2];
    const int* dh_dst = (const int*)d_in[3];
    const int* hh_src = (const int*)d_in[4];
    const int* hh_dst = (const int*)d_in[5];
    const int* hd_src = (const int*)d_in[6];
    const int* hd_dst = (const int*)d_in[7];
    const float* enc_src_w = (const float*)d_in[8];
    const float* enc_src_b = (const float*)d_in[9];
    const float* enc_dst_w = (const float*)d_in[10];
    const float* enc_dst_b = (const float*)d_in[11];
    const float* enc_wl = (const float*)d_in[12];
    const float* enc_bl = (const float*)d_in[13];
    const float* enc_wr = (const float*)d_in[14];
    const float* proc_wl = (const float*)d_in[15];
    const float* proc_bl = (const float*)d_in[16];
    const float* proc_wr = (const float*)d_in[17];
    const float* proc_mlp_w = (const float*)d_in[18];
    const float* proc_mlp_b = (const float*)d_in[19];
    const float* dec_src_w = (const float*)d_in[20];
    const float* dec_src_b = (const float*)d_in[21];
    const float* dec_dst_w = (const float*)d_in[22];
    const float* dec_dst_b = (const float*)d_in[23];
    const float* dec_wl = (const float*)d_in[24];
    const float* dec_bl = (const float*)d_in[25];
    const float* dec_wr = (const float*)d_in[26];
    const float* out_w  = (const float*)d_in[27];
    const float* out_b  = (const float*)d_in[28];
    float* out = (float*)d_out;

    // ---- workspace (bf16 features) ----
    bf16_t* h_a   = (bf16_t*)d_ws;                       // NHID*256
    bf16_t* h_b   = h_a + (size_t)NHID * 256;            // NHID*256
    bf16_t* dmean = h_b + (size_t)NHID * 256;            // NDATA*256
    bf16_t* dbuf  = dmean + (size_t)NDATA * 256;         // NDATA*256 (d, then t in-place)
    bf16_t* wbuf  = dbuf + (size_t)NDATA * 256;          // 8*65536
    int* row_ptr    = (int*)(wbuf + 8 * 65536);          // NDATA+1
    int* cursor     = row_ptr + (NDATA + 1);             // NDATA
    int* sorted_src = cursor + NDATA;                    // NEDGE

    bf16_t* W_enc_wl  = wbuf + 0 * 65536;
    bf16_t* W_enc_wr  = wbuf + 1 * 65536;
    bf16_t* W_proc_wl = wbuf + 2 * 65536;
    bf16_t* W_proc_wr = wbuf + 3 * 65536;
    bf16_t* W_mlp     = wbuf + 4 * 65536;
    bf16_t* W_dec_src = wbuf + 5 * 65536;
    bf16_t* W_dec_wl  = wbuf + 6 * 65536;
    bf16_t* W_dec_wr  = wbuf + 7 * 65536;

    WPtrs wp;
    wp.p[0] = enc_wl;  wp.p[1] = enc_wr;  wp.p[2] = proc_wl; wp.p[3] = proc_wr;
    wp.p[4] = proc_mlp_w; wp.p[5] = dec_src_w; wp.p[6] = dec_wl; wp.p[7] = dec_wr;
    cvt_w_kernel<<<2048, 256, 0, stream>>>(wp, wbuf);

    // ---- encoder ----
    enc_kernel<3><<<512, 256, 0, stream>>>(hidden_x, enc_dst_w, enc_dst_b, h_a, NHID);
    build_csr(dh_src, dh_dst, NHID, NEDGE, cursor, row_ptr, sorted_src, stream);
    csr_sage1_mean<<<NHID / 4, 256, 0, stream>>>(data_x, row_ptr, sorted_src,
                                                 enc_src_w, enc_src_b, h_b, NHID);
    // H1 = gelu(mean1@enc_wl^T + enc_bl + h_a@enc_wr^T) -> h_b
    mfma_gemm<1><<<NHID / 64, 256, 0, stream>>>(h_b, W_enc_wl, h_a, W_enc_wr, enc_bl, h_b);

    // ---- processor ----
    build_csr(hh_src, hh_dst, NHID, NEDGE, cursor, row_ptr, sorted_src, stream);
    csr_gather_mean<<<NHID / 4, 256, 0, stream>>>(h_b, row_ptr, sorted_src, h_a, NHID);
    // gelu(H2) -> h_a
    mfma_gemm<1><<<NHID / 64, 256, 0, stream>>>(h_a, W_proc_wl, h_b, W_proc_wr, proc_bl, h_a);
    // H3 -> h_b
    mfma_gemm<0><<<NHID / 64, 256, 0, stream>>>(h_a, W_mlp, nullptr, nullptr, proc_mlp_b, h_b);
    // s -> h_a
    mfma_gemm<0><<<NHID / 64, 256, 0, stream>>>(h_b, W_dec_src, nullptr, nullptr, dec_src_b, h_a);

    // ---- decoder ----
    build_csr(hd_src, hd_dst, NDATA, NEDGE, cursor, row_ptr, sorted_src, stream);
    csr_gather_mean<<<NDATA / 4, 256, 0, stream>>>(h_a, row_ptr, sorted_src, dmean, NDATA);
    enc_kernel<8><<<2048, 256, 0, stream>>>(data_x, dec_dst_w, dec_dst_b, dbuf, NDATA);
    // t = gelu(dmean@dec_wl^T + dec_bl + dbuf@dec_wr^T) -> dbuf (in place)
    mfma_gemm<1><<<NDATA / 64, 256, 0, stream>>>(dmean, W_dec_wl, dbuf, W_dec_wr, dec_bl, dbuf);
    out_kernel<<<4096, 256, 0, stream>>>(dbuf, out_w, out_b, out, NDATA);
}

// Round 5
// 708.286 us; speedup vs baseline: 7.2987x; 1.6173x over previous
//
#include <hip/hip_runtime.h>

#define NDATA 131072
#define NHID  32768
#define NEDGE 524288

typedef __bf16 bf16_t;
typedef __bf16 bf16x4 __attribute__((ext_vector_type(4)));
typedef __bf16 bf16x8 __attribute__((ext_vector_type(8)));
typedef float  f32x4  __attribute__((ext_vector_type(4)));

__device__ __forceinline__ float gelu_f(float x) {
    return 0.5f * x * (1.0f + erff(x * 0.7071067811865476f));
}

// ---------------- weight fp32 -> bf16 conversion ----------------
struct WPtrs { const float* p[8]; };

__global__ __launch_bounds__(256)
void cvt_w_kernel(WPtrs wp, bf16_t* __restrict__ out) {
    const int i = blockIdx.x * 256 + threadIdx.x;   // 8 * 65536 total
    const int wsel = i >> 16, off = i & 65535;
    out[i] = (bf16_t)wp.p[wsel][off];
}

// ---------------- CSR build ----------------

__global__ __launch_bounds__(256)
void hist_kernel(const int* __restrict__ dst, int* __restrict__ cnt, int ne) {
    const int i = blockIdx.x * 256 + threadIdx.x;
    if (i < ne) atomicAdd(&cnt[dst[i]], 1);
}

// pass 1: per-block (1024 bins) exclusive prescan; block total -> blk
__global__ __launch_bounds__(256)
void scan_blk(const int* __restrict__ cnt, int* __restrict__ pre,
              int* __restrict__ blk) {
    __shared__ int sh[256];
    const int t = threadIdx.x;
    const int base = blockIdx.x * 1024 + t * 4;
    int4 v = *(const int4*)(cnt + base);
    const int s = v.x + v.y + v.z + v.w;
    sh[t] = s;
    __syncthreads();
    for (int off = 1; off < 256; off <<= 1) {
        int other = 0;
        if (t >= off) other = sh[t - off];
        __syncthreads();
        if (t >= off) sh[t] += other;
        __syncthreads();
    }
    const int excl = (t == 0) ? 0 : sh[t - 1];
    int4 o;
    o.x = excl; o.y = o.x + v.x; o.z = o.y + v.y; o.w = o.z + v.z;
    *(int4*)(pre + base) = o;
    if (t == 255) blk[blockIdx.x] = sh[255];
}

// pass 2: single small block scans the <=256 block sums (exclusive, in place)
__global__ __launch_bounds__(256)
void scan_mid(int* __restrict__ blk, int nb) {
    __shared__ int sh[256];
    const int t = threadIdx.x;
    sh[t] = (t < nb) ? blk[t] : 0;
    __syncthreads();
    for (int off = 1; off < 256; off <<= 1) {
        int other = 0;
        if (t >= off) other = sh[t - off];
        __syncthreads();
        if (t >= off) sh[t] += other;
        __syncthreads();
    }
    if (t < nb) blk[t] = (t == 0) ? 0 : sh[t - 1];
}

// pass 3: add block offsets; write row_ptr and cursor
__global__ __launch_bounds__(256)
void scan_add(const int* __restrict__ pre, const int* __restrict__ blk,
              int* __restrict__ row_ptr, int* __restrict__ cursor, int n, int ne) {
    const int t = threadIdx.x;
    const int base = blockIdx.x * 1024 + t * 4;
    const int off = blk[blockIdx.x];
    int4 v = *(const int4*)(pre + base);
    v.x += off; v.y += off; v.z += off; v.w += off;
    *(int4*)(row_ptr + base) = v;
    *(int4*)(cursor + base) = v;
    if (blockIdx.x == 0 && t == 0) row_ptr[n] = ne;
}

__global__ __launch_bounds__(256)
void scatter_kernel(const int* __restrict__ src, const int* __restrict__ dst,
                    int* __restrict__ cursor, int* __restrict__ sorted_src, int ne) {
    const int i = blockIdx.x * 256 + threadIdx.x;
    if (i < ne) {
        const int p = atomicAdd(&cursor[dst[i]], 1);
        sorted_src[p] = src[i];
    }
}

// ---------------- CSR aggregation (mean), bf16 features ----------------

__global__ __launch_bounds__(256)
void csr_gather_mean(const bf16_t* __restrict__ feat, const int* __restrict__ row_ptr,
                     const int* __restrict__ sorted_src, bf16_t* __restrict__ mean, int n) {
    const int lane = threadIdx.x & 63;
    const int w = blockIdx.x * 4 + (threadIdx.x >> 6);
    if (w >= n) return;
    const int e0 = row_ptr[w], e1 = row_ptr[w + 1];
    float ax = 0.f, ay = 0.f, az = 0.f, aw = 0.f;
    int e = e0;
    for (; e + 1 < e1; e += 2) {
        const int s0 = sorted_src[e], s1 = sorted_src[e + 1];
        const bf16x4 v0 = *(const bf16x4*)(feat + (size_t)s0 * 256 + lane * 4);
        const bf16x4 v1 = *(const bf16x4*)(feat + (size_t)s1 * 256 + lane * 4);
        ax += (float)v0[0] + (float)v1[0]; ay += (float)v0[1] + (float)v1[1];
        az += (float)v0[2] + (float)v1[2]; aw += (float)v0[3] + (float)v1[3];
    }
    if (e < e1) {
        const int s0 = sorted_src[e];
        const bf16x4 v0 = *(const bf16x4*)(feat + (size_t)s0 * 256 + lane * 4);
        ax += (float)v0[0]; ay += (float)v0[1]; az += (float)v0[2]; aw += (float)v0[3];
    }
    const float ic = 1.0f / fmaxf((float)(e1 - e0), 1.0f);
    bf16x4 r;
    r[0] = (bf16_t)(ax * ic); r[1] = (bf16_t)(ay * ic);
    r[2] = (bf16_t)(az * ic); r[3] = (bf16_t)(aw * ic);
    *(bf16x4*)(mean + (size_t)w * 256 + lane * 4) = r;
}

// sage1: message = gelu(data_x[src] @ enc_src_w^T + enc_src_b) computed on the fly (fp32 math)
__global__ __launch_bounds__(256)
void csr_sage1_mean(const float* __restrict__ data_x, const int* __restrict__ row_ptr,
                    const int* __restrict__ sorted_src, const float* __restrict__ w,
                    const float* __restrict__ b, bf16_t* __restrict__ mean, int n) {
    const int lane = threadIdx.x & 63;
    float wr[4][8], bias[4];
    #pragma unroll
    for (int r = 0; r < 4; ++r) {
        #pragma unroll
        for (int j = 0; j < 8; ++j) wr[r][j] = w[(lane * 4 + r) * 8 + j];
        bias[r] = b[lane * 4 + r];
    }
    const int wv = blockIdx.x * 4 + (threadIdx.x >> 6);
    if (wv >= n) return;
    const int e0 = row_ptr[wv], e1 = row_ptr[wv + 1];
    float acc[4] = {0.f, 0.f, 0.f, 0.f};
    for (int e = e0; e < e1; ++e) {
        const int s = sorted_src[e];
        const float4 xa = *(const float4*)(data_x + (size_t)s * 8);
        const float4 xb = *(const float4*)(data_x + (size_t)s * 8 + 4);
        #pragma unroll
        for (int r = 0; r < 4; ++r) {
            float m = bias[r] + xa.x * wr[r][0] + xa.y * wr[r][1] + xa.z * wr[r][2] + xa.w * wr[r][3]
                              + xb.x * wr[r][4] + xb.y * wr[r][5] + xb.z * wr[r][6] + xb.w * wr[r][7];
            acc[r] += gelu_f(m);
        }
    }
    const float ic = 1.0f / fmaxf((float)(e1 - e0), 1.0f);
    bf16x4 r4;
    #pragma unroll
    for (int r = 0; r < 4; ++r) r4[r] = (bf16_t)(acc[r] * ic);
    *(bf16x4*)(mean + (size_t)wv * 256 + lane * 4) = r4;
}

// ---------------- small-K encoder (fp32 math, bf16 out) ----------------
template<int K>
__global__ __launch_bounds__(256)
void enc_kernel(const float* __restrict__ x, const float* __restrict__ w,
                const float* __restrict__ b, bf16_t* __restrict__ out, int n) {
    __shared__ float ws[K * 256];
    const int t = threadIdx.x;
    #pragma unroll
    for (int j = 0; j < K; ++j) ws[j * 256 + t] = w[t * K + j];
    const float bias = b[t];
    __syncthreads();
    for (int node = blockIdx.x; node < n; node += gridDim.x) {
        const float* xr = x + (size_t)node * K;
        float acc = bias;
        #pragma unroll
        for (int j = 0; j < K; ++j) acc += xr[j] * ws[j * 256 + t];
        out[(size_t)node * 256 + t] = (bf16_t)gelu_f(acc);
    }
}

// ---------------- MFMA bf16 GEMM ----------------
// C[M,256] = gelu( bias + A1 @ W1^T [+ A2 @ W2^T] )
// BM=64, BN=256, BK=32; 4 waves, wave w owns cols [w*64, w*64+64).
#define ASTR 40   // LDS row stride in bf16 (80 B)
template<int DUAL>
__global__ __launch_bounds__(256)
void mfma_gemm(const bf16_t* __restrict__ A1, const bf16_t* __restrict__ W1,
               const bf16_t* __restrict__ A2, const bf16_t* __restrict__ W2,
               const float* __restrict__ bias, bf16_t* __restrict__ C) {
    __shared__ bf16_t As[64 * ASTR];
    __shared__ bf16_t Bs[256 * ASTR];
    const int t = threadIdx.x;
    const int w = t >> 6, lane = t & 63;
    const int l15 = lane & 15, l4 = lane >> 4;
    const int m0 = blockIdx.x * 64;

    f32x4 acc[4][4];
    #pragma unroll
    for (int nb = 0; nb < 4; ++nb) {
        const float bv = bias[w * 64 + nb * 16 + l15];
        #pragma unroll
        for (int m = 0; m < 4; ++m) {
            acc[m][nb][0] = bv; acc[m][nb][1] = bv; acc[m][nb][2] = bv; acc[m][nb][3] = bv;
        }
    }

    const int ar = t >> 2, aq = t & 3;
    #pragma unroll
    for (int p = 0; p <= DUAL; ++p) {
        const bf16_t* Ap = p ? A2 : A1;
        const bf16_t* Wp = p ? W2 : W1;
        for (int kt = 0; kt < 8; ++kt) {
            const int k0 = kt * 32;
            __syncthreads();
            *(bf16x8*)(&As[ar * ASTR + aq * 8]) =
                *(const bf16x8*)(Ap + (size_t)(m0 + ar) * 256 + k0 + aq * 8);
            {
                const bf16_t* wrp = Wp + (size_t)t * 256 + k0;
                #pragma unroll
                for (int q = 0; q < 4; ++q)
                    *(bf16x8*)(&Bs[t * ASTR + q * 8]) = *(const bf16x8*)(wrp + q * 8);
            }
            __syncthreads();
            bf16x8 af[4], bfr[4];
            #pragma unroll
            for (int m = 0; m < 4; ++m)
                af[m] = *(const bf16x8*)(&As[(m * 16 + l15) * ASTR + l4 * 8]);
            #pragma unroll
            for (int nb = 0; nb < 4; ++nb)
                bfr[nb] = *(const bf16x8*)(&Bs[(w * 64 + nb * 16 + l15) * ASTR + l4 * 8]);
            #pragma unroll
            for (int m = 0; m < 4; ++m)
                #pragma unroll
                for (int nb = 0; nb < 4; ++nb)
                    acc[m][nb] = __builtin_amdgcn_mfma_f32_16x16x32_bf16(af[m], bfr[nb], acc[m][nb], 0, 0, 0);
        }
    }

    #pragma unroll
    for (int m = 0; m < 4; ++m) {
        #pragma unroll
        for (int nb = 0; nb < 4; ++nb) {
            const int col = w * 64 + nb * 16 + l15;
            #pragma unroll
            for (int i = 0; i < 4; ++i) {
                const int row = m0 + m * 16 + l4 * 4 + i;
                C[(size_t)row * 256 + col] = (bf16_t)gelu_f(acc[m][nb][i]);
            }
        }
    }
}

// out[n,8] = t_in[n,256](bf16) @ out_w[8,256]^T + out_b
__global__ __launch_bounds__(256)
void out_kernel(const bf16_t* __restrict__ tin, const float* __restrict__ ow,
                const float* __restrict__ ob, float* __restrict__ out, int n) {
    const int lane = threadIdx.x & 63;
    const int wv   = threadIdx.x >> 6;
    float owv[8][4];
    #pragma unroll
    for (int o = 0; o < 8; ++o) {
        float4 q = *(const float4*)(ow + o * 256 + lane * 4);
        owv[o][0] = q.x; owv[o][1] = q.y; owv[o][2] = q.z; owv[o][3] = q.w;
    }
    for (int row = blockIdx.x * 4 + wv; row < n; row += gridDim.x * 4) {
        const bf16x4 v = *(const bf16x4*)(tin + (size_t)row * 256 + lane * 4);
        const float v0 = (float)v[0], v1 = (float)v[1], v2 = (float)v[2], v3 = (float)v[3];
        float p[8];
        #pragma unroll
        for (int o = 0; o < 8; ++o)
            p[o] = v0 * owv[o][0] + v1 * owv[o][1] + v2 * owv[o][2] + v3 * owv[o][3];
        #pragma unroll
        for (int m = 1; m < 64; m <<= 1) {
            #pragma unroll
            for (int o = 0; o < 8; ++o) p[o] += __shfl_xor(p[o], m, 64);
        }
        if (lane == 0) {
            #pragma unroll
            for (int o = 0; o < 8; ++o) out[(size_t)row * 8 + o] = p[o] + ob[o];
        }
    }
}

// ---------------- launch ----------------

static void build_csr(const int* src, const int* dst, int n, int ne,
                      int* cursor, int* row_ptr, int* sorted_src, int* blk_sums,
                      hipStream_t stream) {
    hipMemsetAsync(cursor, 0, (size_t)n * sizeof(int), stream);
    hist_kernel<<<(ne + 255) / 256, 256, 0, stream>>>(dst, cursor, ne);
    const int nb = n / 1024;
    scan_blk<<<nb, 256, 0, stream>>>(cursor, row_ptr, blk_sums);
    scan_mid<<<1, 256, 0, stream>>>(blk_sums, nb);
    scan_add<<<nb, 256, 0, stream>>>(row_ptr, blk_sums, row_ptr, cursor, n, ne);
    scatter_kernel<<<(ne + 255) / 256, 256, 0, stream>>>(src, dst, cursor, sorted_src, ne);
}

extern "C" void kernel_launch(void* const* d_in, const int* in_sizes, int n_in,
                              void* d_out, int out_size, void* d_ws, size_t ws_size,
                              hipStream_t stream) {
    const float* data_x   = (const float*)d_in[0];
    const float* hidden_x = (const float*)d_in[1];
    const int* dh_src = (const int*)d_in[2];
    const int* dh_dst = (const int*)d_in[3];
    const int* hh_src = (const int*)d_in[4];
    const int* hh_dst = (const int*)d_in[5];
    const int* hd_src = (const int*)d_in[6];
    const int* hd_dst = (const int*)d_in[7];
    const float* enc_src_w = (const float*)d_in[8];
    const float* enc_src_b = (const float*)d_in[9];
    const float* enc_dst_w = (const float*)d_in[10];
    const float* enc_dst_b = (const float*)d_in[11];
    const float* enc_wl = (const float*)d_in[12];
    const float* enc_bl = (const float*)d_in[13];
    const float* enc_wr = (const float*)d_in[14];
    const float* proc_wl = (const float*)d_in[15];
    const float* proc_bl = (const float*)d_in[16];
    const float* proc_wr = (const float*)d_in[17];
    const float* proc_mlp_w = (const float*)d_in[18];
    const float* proc_mlp_b = (const float*)d_in[19];
    const float* dec_src_w = (const float*)d_in[20];
    const float* dec_src_b = (const float*)d_in[21];
    const float* dec_dst_w = (const float*)d_in[22];
    const float* dec_dst_b = (const float*)d_in[23];
    const float* dec_wl = (const float*)d_in[24];
    const float* dec_bl = (const float*)d_in[25];
    const float* dec_wr = (const float*)d_in[26];
    const float* out_w  = (const float*)d_in[27];
    const float* out_b  = (const float*)d_in[28];
    float* out = (float*)d_out;

    // ---- workspace (bf16 features) ----
    bf16_t* h_a   = (bf16_t*)d_ws;                       // NHID*256
    bf16_t* h_b   = h_a + (size_t)NHID * 256;            // NHID*256
    bf16_t* dmean = h_b + (size_t)NHID * 256;            // NDATA*256
    bf16_t* dbuf  = dmean + (size_t)NDATA * 256;         // NDATA*256
    bf16_t* wbuf  = dbuf + (size_t)NDATA * 256;          // 8*65536
    int* row_ptr    = (int*)(wbuf + 8 * 65536);          // NDATA+1
    int* cursor     = row_ptr + (NDATA + 1);             // NDATA
    int* sorted_src = cursor + NDATA;                    // NEDGE
    int* blk_sums   = sorted_src + NEDGE;                // 256

    bf16_t* W_enc_wl  = wbuf + 0 * 65536;
    bf16_t* W_enc_wr  = wbuf + 1 * 65536;
    bf16_t* W_proc_wl = wbuf + 2 * 65536;
    bf16_t* W_proc_wr = wbuf + 3 * 65536;
    bf16_t* W_mlp     = wbuf + 4 * 65536;
    bf16_t* W_dec_src = wbuf + 5 * 65536;
    bf16_t* W_dec_wl  = wbuf + 6 * 65536;
    bf16_t* W_dec_wr  = wbuf + 7 * 65536;

    WPtrs wp;
    wp.p[0] = enc_wl;  wp.p[1] = enc_wr;  wp.p[2] = proc_wl; wp.p[3] = proc_wr;
    wp.p[4] = proc_mlp_w; wp.p[5] = dec_src_w; wp.p[6] = dec_wl; wp.p[7] = dec_wr;
    cvt_w_kernel<<<2048, 256, 0, stream>>>(wp, wbuf);

    // ---- encoder ----
    enc_kernel<3><<<512, 256, 0, stream>>>(hidden_x, enc_dst_w, enc_dst_b, h_a, NHID);
    build_csr(dh_src, dh_dst, NHID, NEDGE, cursor, row_ptr, sorted_src, blk_sums, stream);
    csr_sage1_mean<<<NHID / 4, 256, 0, stream>>>(data_x, row_ptr, sorted_src,
                                                 enc_src_w, enc_src_b, h_b, NHID);
    mfma_gemm<1><<<NHID / 64, 256, 0, stream>>>(h_b, W_enc_wl, h_a, W_enc_wr, enc_bl, h_b);

    // ---- processor ----
    build_csr(hh_src, hh_dst, NHID, NEDGE, cursor, row_ptr, sorted_src, blk_sums, stream);
    csr_gather_mean<<<NHID / 4, 256, 0, stream>>>(h_b, row_ptr, sorted_src, h_a, NHID);
    mfma_gemm<1><<<NHID / 64, 256, 0, stream>>>(h_a, W_proc_wl, h_b, W_proc_wr, proc_bl, h_a);
    mfma_gemm<0><<<NHID / 64, 256, 0, stream>>>(h_a, W_mlp, nullptr, nullptr, proc_mlp_b, h_b);
    mfma_gemm<0><<<NHID / 64, 256, 0, stream>>>(h_b, W_dec_src, nullptr, nullptr, dec_src_b, h_a);

    // ---- decoder ----
    build_csr(hd_src, hd_dst, NDATA, NEDGE, cursor, row_ptr, sorted_src, blk_sums, stream);
    csr_gather_mean<<<NDATA / 4, 256, 0, stream>>>(h_a, row_ptr, sorted_src, dmean, NDATA);
    enc_kernel<8><<<2048, 256, 0, stream>>>(data_x, dec_dst_w, dec_dst_b, dbuf, NDATA);
    mfma_gemm<1><<<NDATA / 64, 256, 0, stream>>>(dmean, W_dec_wl, dbuf, W_dec_wr, dec_bl, dbuf);
    out_kernel<<<4096, 256, 0, stream>>>(dbuf, out_w, out_b, out, NDATA);
}

// Round 6
// 615.554 us; speedup vs baseline: 8.3983x; 1.1506x over previous
//
#include <hip/hip_runtime.h>

#define NDATA 131072
#define NHID  32768
#define NEDGE 524288

typedef __bf16 bf16_t;
typedef __bf16 bf16x4 __attribute__((ext_vector_type(4)));
typedef __bf16 bf16x8 __attribute__((ext_vector_type(8)));
typedef float  f32x4  __attribute__((ext_vector_type(4)));

__device__ __forceinline__ float gelu_f(float x) {
    return 0.5f * x * (1.0f + erff(x * 0.7071067811865476f));
}

// ---------------- weight fp32 -> bf16 conversion ----------------
struct WPtrs { const float* p[8]; };

__global__ __launch_bounds__(256)
void cvt_w_kernel(WPtrs wp, bf16_t* __restrict__ out) {
    const int i = blockIdx.x * 256 + threadIdx.x;   // 8 * 65536 total
    const int wsel = i >> 16, off = i & 65535;
    out[i] = (bf16_t)wp.p[wsel][off];
}

// ---------------- CSR build ----------------

__global__ __launch_bounds__(256)
void hist_kernel(const int* __restrict__ dst, int* __restrict__ cnt, int ne) {
    const int i = blockIdx.x * 256 + threadIdx.x;
    if (i < ne) atomicAdd(&cnt[dst[i]], 1);
}

__global__ __launch_bounds__(256)
void scan_blk(const int* __restrict__ cnt, int* __restrict__ pre,
              int* __restrict__ blk) {
    __shared__ int sh[256];
    const int t = threadIdx.x;
    const int base = blockIdx.x * 1024 + t * 4;
    int4 v = *(const int4*)(cnt + base);
    const int s = v.x + v.y + v.z + v.w;
    sh[t] = s;
    __syncthreads();
    for (int off = 1; off < 256; off <<= 1) {
        int other = 0;
        if (t >= off) other = sh[t - off];
        __syncthreads();
        if (t >= off) sh[t] += other;
        __syncthreads();
    }
    const int excl = (t == 0) ? 0 : sh[t - 1];
    int4 o;
    o.x = excl; o.y = o.x + v.x; o.z = o.y + v.y; o.w = o.z + v.z;
    *(int4*)(pre + base) = o;
    if (t == 255) blk[blockIdx.x] = sh[255];
}

__global__ __launch_bounds__(256)
void scan_mid(int* __restrict__ blk, int nb) {
    __shared__ int sh[256];
    const int t = threadIdx.x;
    sh[t] = (t < nb) ? blk[t] : 0;
    __syncthreads();
    for (int off = 1; off < 256; off <<= 1) {
        int other = 0;
        if (t >= off) other = sh[t - off];
        __syncthreads();
        if (t >= off) sh[t] += other;
        __syncthreads();
    }
    if (t < nb) blk[t] = (t == 0) ? 0 : sh[t - 1];
}

__global__ __launch_bounds__(256)
void scan_add(const int* __restrict__ pre, const int* __restrict__ blk,
              int* __restrict__ row_ptr, int* __restrict__ cursor, int n, int ne) {
    const int t = threadIdx.x;
    const int base = blockIdx.x * 1024 + t * 4;
    const int off = blk[blockIdx.x];
    int4 v = *(const int4*)(pre + base);
    v.x += off; v.y += off; v.z += off; v.w += off;
    *(int4*)(row_ptr + base) = v;
    *(int4*)(cursor + base) = v;
    if (blockIdx.x == 0 && t == 0) row_ptr[n] = ne;
}

__global__ __launch_bounds__(256)
void scatter_kernel(const int* __restrict__ src, const int* __restrict__ dst,
                    int* __restrict__ cursor, int* __restrict__ sorted_src, int ne) {
    const int i = blockIdx.x * 256 + threadIdx.x;
    if (i < ne) {
        const int p = atomicAdd(&cursor[dst[i]], 1);
        sorted_src[p] = src[i];
    }
}

// ---------------- CSR aggregation (mean), bf16 features ----------------
// wave per dst node; wave processes 2 edges at a time, 16 B per lane.
__global__ __launch_bounds__(256)
void csr_gather_mean(const bf16_t* __restrict__ feat, const int* __restrict__ row_ptr,
                     const int* __restrict__ sorted_src, bf16_t* __restrict__ mean, int n) {
    const int lane = threadIdx.x & 63;
    const int half = lane >> 5;          // which edge of the pair
    const int col8 = (lane & 31) * 8;    // 8 bf16 = 16 B
    const int w = blockIdx.x * 4 + (threadIdx.x >> 6);
    if (w >= n) return;
    const int e0 = row_ptr[w], e1 = row_ptr[w + 1];
    float acc[8] = {0.f, 0.f, 0.f, 0.f, 0.f, 0.f, 0.f, 0.f};
    for (int e = e0 + half; e < e1; e += 2) {
        const int s = sorted_src[e];
        const bf16x8 v = *(const bf16x8*)(feat + (size_t)s * 256 + col8);
        #pragma unroll
        for (int j = 0; j < 8; ++j) acc[j] += (float)v[j];
    }
    #pragma unroll
    for (int j = 0; j < 8; ++j) acc[j] += __shfl_xor(acc[j], 32, 64);
    if (half == 0) {
        const float ic = 1.0f / fmaxf((float)(e1 - e0), 1.0f);
        bf16x8 r;
        #pragma unroll
        for (int j = 0; j < 8; ++j) r[j] = (bf16_t)(acc[j] * ic);
        *(bf16x8*)(mean + (size_t)w * 256 + col8) = r;
    }
}

// ---------------- small-K encoder (fp32 math, bf16 out) ----------------
template<int K>
__global__ __launch_bounds__(256)
void enc_kernel(const float* __restrict__ x, const float* __restrict__ w,
                const float* __restrict__ b, bf16_t* __restrict__ out, int n) {
    __shared__ float ws[K * 256];
    const int t = threadIdx.x;
    #pragma unroll
    for (int j = 0; j < K; ++j) ws[j * 256 + t] = w[t * K + j];
    const float bias = b[t];
    __syncthreads();
    for (int node = blockIdx.x; node < n; node += gridDim.x) {
        const float* xr = x + (size_t)node * K;
        float acc = bias;
        #pragma unroll
        for (int j = 0; j < K; ++j) acc += xr[j] * ws[j * 256 + t];
        out[(size_t)node * 256 + t] = (bf16_t)gelu_f(acc);
    }
}

// ---------------- MFMA bf16 GEMM ----------------
// C[M,256] = gelu( bias + A1 @ W1^T [+ A2 @ W2^T] )
// BM=64, BN=256, BK=32; 4 waves, wave w owns cols [w*64, w*64+64).
#define ASTR 40   // LDS row stride in bf16 (80 B)
template<int DUAL>
__global__ __launch_bounds__(256)
void mfma_gemm(const bf16_t* __restrict__ A1, const bf16_t* __restrict__ W1,
               const bf16_t* __restrict__ A2, const bf16_t* __restrict__ W2,
               const float* __restrict__ bias, bf16_t* __restrict__ C) {
    __shared__ bf16_t As[64 * ASTR];
    __shared__ bf16_t Bs[256 * ASTR];
    const int t = threadIdx.x;
    const int w = t >> 6, lane = t & 63;
    const int l15 = lane & 15, l4 = lane >> 4;
    const int m0 = blockIdx.x * 64;

    f32x4 acc[4][4];
    #pragma unroll
    for (int nb = 0; nb < 4; ++nb) {
        const float bv = bias[w * 64 + nb * 16 + l15];
        #pragma unroll
        for (int m = 0; m < 4; ++m) {
            acc[m][nb][0] = bv; acc[m][nb][1] = bv; acc[m][nb][2] = bv; acc[m][nb][3] = bv;
        }
    }

    const int ar = t >> 2, aq = t & 3;
    #pragma unroll
    for (int p = 0; p <= DUAL; ++p) {
        const bf16_t* Ap = p ? A2 : A1;
        const bf16_t* Wp = p ? W2 : W1;
        for (int kt = 0; kt < 8; ++kt) {
            const int k0 = kt * 32;
            __syncthreads();
            *(bf16x8*)(&As[ar * ASTR + aq * 8]) =
                *(const bf16x8*)(Ap + (size_t)(m0 + ar) * 256 + k0 + aq * 8);
            {
                const bf16_t* wrp = Wp + (size_t)t * 256 + k0;
                #pragma unroll
                for (int q = 0; q < 4; ++q)
                    *(bf16x8*)(&Bs[t * ASTR + q * 8]) = *(const bf16x8*)(wrp + q * 8);
            }
            __syncthreads();
            bf16x8 af[4], bfr[4];
            #pragma unroll
            for (int m = 0; m < 4; ++m)
                af[m] = *(const bf16x8*)(&As[(m * 16 + l15) * ASTR + l4 * 8]);
            #pragma unroll
            for (int nb = 0; nb < 4; ++nb)
                bfr[nb] = *(const bf16x8*)(&Bs[(w * 64 + nb * 16 + l15) * ASTR + l4 * 8]);
            #pragma unroll
            for (int m = 0; m < 4; ++m)
                #pragma unroll
                for (int nb = 0; nb < 4; ++nb)
                    acc[m][nb] = __builtin_amdgcn_mfma_f32_16x16x32_bf16(af[m], bfr[nb], acc[m][nb], 0, 0, 0);
        }
    }

    #pragma unroll
    for (int m = 0; m < 4; ++m) {
        #pragma unroll
        for (int nb = 0; nb < 4; ++nb) {
            const int col = w * 64 + nb * 16 + l15;
            #pragma unroll
            for (int i = 0; i < 4; ++i) {
                const int row = m0 + m * 16 + l4 * 4 + i;
                C[(size_t)row * 256 + col] = (bf16_t)gelu_f(acc[m][nb][i]);
            }
        }
    }
}

// ---------------- fused decoder GEMM ----------------
// t = gelu(dec_bl + A1@W1^T + d@W2^T), d = gelu(data_x@Wd^T+bd) on the fly,
// out = t @ ow^T + ob   (shuffle + LDS cross-wave reduce epilogue)
__global__ __launch_bounds__(256)
void dec_gemm(const bf16_t* __restrict__ A1, const bf16_t* __restrict__ W1,
              const float* __restrict__ xdat, const float* __restrict__ Wd,
              const float* __restrict__ bd, const bf16_t* __restrict__ W2,
              const float* __restrict__ bias, const float* __restrict__ ow,
              const float* __restrict__ ob, float* __restrict__ out) {
    __shared__ bf16_t As[64 * ASTR];       // 5 KB
    __shared__ bf16_t Bs[256 * ASTR];      // 20 KB
    __shared__ float xs[64 * 8];           // 2 KB  (data_x rows of this block)
    __shared__ float wds[256 * 8];         // 8 KB  (dec_dst_w)
    __shared__ float bds[256];             // 1 KB
    __shared__ float sh_out[4][64][8];     // 8 KB  (per-wave partial out)
    const int t = threadIdx.x;
    const int w = t >> 6, lane = t & 63;
    const int l15 = lane & 15, l4 = lane >> 4;
    const int m0 = blockIdx.x * 64;

    // stage xdat rows (contiguous 512 f32) and Wd (2048 f32) + bd
    if (t < 128) *(float4*)(&xs[t * 4]) = *(const float4*)(xdat + (size_t)m0 * 8 + t * 4);
    *(float4*)(&wds[t * 8])     = *(const float4*)(Wd + t * 8);
    *(float4*)(&wds[t * 8 + 4]) = *(const float4*)(Wd + t * 8 + 4);
    bds[t] = bd[t];

    float ow_reg[8][4];
    #pragma unroll
    for (int o = 0; o < 8; ++o)
        #pragma unroll
        for (int nb = 0; nb < 4; ++nb)
            ow_reg[o][nb] = ow[o * 256 + w * 64 + nb * 16 + l15];

    f32x4 acc[4][4];
    #pragma unroll
    for (int nb = 0; nb < 4; ++nb) {
        const float bv = bias[w * 64 + nb * 16 + l15];
        #pragma unroll
        for (int m = 0; m < 4; ++m) {
            acc[m][nb][0] = bv; acc[m][nb][1] = bv; acc[m][nb][2] = bv; acc[m][nb][3] = bv;
        }
    }

    const int ar = t >> 2, aq = t & 3;
    #pragma unroll
    for (int p = 0; p < 2; ++p) {
        const bf16_t* Wp = p ? W2 : W1;
        for (int kt = 0; kt < 8; ++kt) {
            const int k0 = kt * 32;
            __syncthreads();
            if (p == 0) {
                *(bf16x8*)(&As[ar * ASTR + aq * 8]) =
                    *(const bf16x8*)(A1 + (size_t)(m0 + ar) * 256 + k0 + aq * 8);
            } else {
                // compute d tile: rows ar, k = k0 + aq*8 + kk
                bf16x8 dv;
                #pragma unroll
                for (int kk = 0; kk < 8; ++kk) {
                    const int k = k0 + aq * 8 + kk;
                    float val = bds[k];
                    #pragma unroll
                    for (int j = 0; j < 8; ++j) val += xs[ar * 8 + j] * wds[k * 8 + j];
                    dv[kk] = (bf16_t)gelu_f(val);
                }
                *(bf16x8*)(&As[ar * ASTR + aq * 8]) = dv;
            }
            {
                const bf16_t* wrp = Wp + (size_t)t * 256 + k0;
                #pragma unroll
                for (int q = 0; q < 4; ++q)
                    *(bf16x8*)(&Bs[t * ASTR + q * 8]) = *(const bf16x8*)(wrp + q * 8);
            }
            __syncthreads();
            bf16x8 af[4], bfr[4];
            #pragma unroll
            for (int m = 0; m < 4; ++m)
                af[m] = *(const bf16x8*)(&As[(m * 16 + l15) * ASTR + l4 * 8]);
            #pragma unroll
            for (int nb = 0; nb < 4; ++nb)
                bfr[nb] = *(const bf16x8*)(&Bs[(w * 64 + nb * 16 + l15) * ASTR + l4 * 8]);
            #pragma unroll
            for (int m = 0; m < 4; ++m)
                #pragma unroll
                for (int nb = 0; nb < 4; ++nb)
                    acc[m][nb] = __builtin_amdgcn_mfma_f32_16x16x32_bf16(af[m], bfr[nb], acc[m][nb], 0, 0, 0);
        }
    }

    // epilogue: t_val = gelu(acc); partial out = t_val @ ow^T over this wave's 64 cols
    #pragma unroll
    for (int m = 0; m < 4; ++m) {
        #pragma unroll
        for (int i = 0; i < 4; ++i) {
            float tv[4];
            #pragma unroll
            for (int nb = 0; nb < 4; ++nb) tv[nb] = gelu_f(acc[m][nb][i]);
            float p[8];
            #pragma unroll
            for (int o = 0; o < 8; ++o)
                p[o] = tv[0] * ow_reg[o][0] + tv[1] * ow_reg[o][1]
                     + tv[2] * ow_reg[o][2] + tv[3] * ow_reg[o][3];
            // reduce over the 16 lanes of the l15 group
            #pragma unroll
            for (int msk = 1; msk < 16; msk <<= 1)
                #pragma unroll
                for (int o = 0; o < 8; ++o) p[o] += __shfl_xor(p[o], msk, 64);
            if (l15 == 0) {
                const int row = m * 16 + l4 * 4 + i;
                #pragma unroll
                for (int o = 0; o < 8; ++o) sh_out[w][row][o] = p[o];
            }
        }
    }
    __syncthreads();
    // cross-wave reduce: 512 (row,o) entries / 256 threads = 2 each
    #pragma unroll
    for (int q = 0; q < 2; ++q) {
        const int idx = t * 2 + q;
        const int row = idx >> 3, o = idx & 7;
        const float v = sh_out[0][row][o] + sh_out[1][row][o]
                      + sh_out[2][row][o] + sh_out[3][row][o] + ob[o];
        out[(size_t)(m0 + row) * 8 + o] = v;
    }
}

// ---------------- launch ----------------

static void build_csr(const int* src, const int* dst, int n, int ne,
                      int* cursor, int* row_ptr, int* sorted_src, int* blk_sums,
                      hipStream_t stream) {
    hipMemsetAsync(cursor, 0, (size_t)n * sizeof(int), stream);
    hist_kernel<<<(ne + 255) / 256, 256, 0, stream>>>(dst, cursor, ne);
    const int nb = n / 1024;
    scan_blk<<<nb, 256, 0, stream>>>(cursor, row_ptr, blk_sums);
    scan_mid<<<1, 256, 0, stream>>>(blk_sums, nb);
    scan_add<<<nb, 256, 0, stream>>>(row_ptr, blk_sums, row_ptr, cursor, n, ne);
    scatter_kernel<<<(ne + 255) / 256, 256, 0, stream>>>(src, dst, cursor, sorted_src, ne);
}

extern "C" void kernel_launch(void* const* d_in, const int* in_sizes, int n_in,
                              void* d_out, int out_size, void* d_ws, size_t ws_size,
                              hipStream_t stream) {
    const float* data_x   = (const float*)d_in[0];
    const float* hidden_x = (const float*)d_in[1];
    const int* dh_src = (const int*)d_in[2];
    const int* dh_dst = (const int*)d_in[3];
    const int* hh_src = (const int*)d_in[4];
    const int* hh_dst = (const int*)d_in[5];
    const int* hd_src = (const int*)d_in[6];
    const int* hd_dst = (const int*)d_in[7];
    const float* enc_src_w = (const float*)d_in[8];
    const float* enc_src_b = (const float*)d_in[9];
    const float* enc_dst_w = (const float*)d_in[10];
    const float* enc_dst_b = (const float*)d_in[11];
    const float* enc_wl = (const float*)d_in[12];
    const float* enc_bl = (const float*)d_in[13];
    const float* enc_wr = (const float*)d_in[14];
    const float* proc_wl = (const float*)d_in[15];
    const float* proc_bl = (const float*)d_in[16];
    const float* proc_wr = (const float*)d_in[17];
    const float* proc_mlp_w = (const float*)d_in[18];
    const float* proc_mlp_b = (const float*)d_in[19];
    const float* dec_src_w = (const float*)d_in[20];
    const float* dec_src_b = (const float*)d_in[21];
    const float* dec_dst_w = (const float*)d_in[22];
    const float* dec_dst_b = (const float*)d_in[23];
    const float* dec_wl = (const float*)d_in[24];
    const float* dec_bl = (const float*)d_in[25];
    const float* dec_wr = (const float*)d_in[26];
    const float* out_w  = (const float*)d_in[27];
    const float* out_b  = (const float*)d_in[28];
    float* out = (float*)d_out;

    // ---- workspace (bf16 features) ----
    bf16_t* h_a   = (bf16_t*)d_ws;                       // NHID*256
    bf16_t* h_b   = h_a + (size_t)NHID * 256;            // NHID*256
    bf16_t* h_msg = h_b + (size_t)NHID * 256;            // NDATA*256 (sage1 messages)
    bf16_t* dmean = h_msg + (size_t)NDATA * 256;         // NDATA*256
    bf16_t* wbuf  = dmean + (size_t)NDATA * 256;         // 8*65536
    int* row_ptr    = (int*)(wbuf + 8 * 65536);          // NDATA+1
    int* cursor     = row_ptr + (NDATA + 1);             // NDATA
    int* sorted_src = cursor + NDATA;                    // NEDGE
    int* blk_sums   = sorted_src + NEDGE;                // 256

    bf16_t* W_enc_wl  = wbuf + 0 * 65536;
    bf16_t* W_enc_wr  = wbuf + 1 * 65536;
    bf16_t* W_proc_wl = wbuf + 2 * 65536;
    bf16_t* W_proc_wr = wbuf + 3 * 65536;
    bf16_t* W_mlp     = wbuf + 4 * 65536;
    bf16_t* W_dec_src = wbuf + 5 * 65536;
    bf16_t* W_dec_wl  = wbuf + 6 * 65536;
    bf16_t* W_dec_wr  = wbuf + 7 * 65536;

    WPtrs wp;
    wp.p[0] = enc_wl;  wp.p[1] = enc_wr;  wp.p[2] = proc_wl; wp.p[3] = proc_wr;
    wp.p[4] = proc_mlp_w; wp.p[5] = dec_src_w; wp.p[6] = dec_wl; wp.p[7] = dec_wr;
    cvt_w_kernel<<<2048, 256, 0, stream>>>(wp, wbuf);

    // ---- encoder ----
    enc_kernel<3><<<512, 256, 0, stream>>>(hidden_x, enc_dst_w, enc_dst_b, h_a, NHID);
    enc_kernel<8><<<2048, 256, 0, stream>>>(data_x, enc_src_w, enc_src_b, h_msg, NDATA);
    build_csr(dh_src, dh_dst, NHID, NEDGE, cursor, row_ptr, sorted_src, blk_sums, stream);
    csr_gather_mean<<<NHID / 4, 256, 0, stream>>>(h_msg, row_ptr, sorted_src, h_b, NHID);
    mfma_gemm<1><<<NHID / 64, 256, 0, stream>>>(h_b, W_enc_wl, h_a, W_enc_wr, enc_bl, h_b);

    // ---- processor ----
    build_csr(hh_src, hh_dst, NHID, NEDGE, cursor, row_ptr, sorted_src, blk_sums, stream);
    csr_gather_mean<<<NHID / 4, 256, 0, stream>>>(h_b, row_ptr, sorted_src, h_a, NHID);
    mfma_gemm<1><<<NHID / 64, 256, 0, stream>>>(h_a, W_proc_wl, h_b, W_proc_wr, proc_bl, h_a);
    mfma_gemm<0><<<NHID / 64, 256, 0, stream>>>(h_a, W_mlp, nullptr, nullptr, proc_mlp_b, h_b);
    mfma_gemm<0><<<NHID / 64, 256, 0, stream>>>(h_b, W_dec_src, nullptr, nullptr, dec_src_b, h_a);

    // ---- decoder (fully fused) ----
    build_csr(hd_src, hd_dst, NDATA, NEDGE, cursor, row_ptr, sorted_src, blk_sums, stream);
    csr_gather_mean<<<NDATA / 4, 256, 0, stream>>>(h_a, row_ptr, sorted_src, dmean, NDATA);
    dec_gemm<<<NDATA / 64, 256, 0, stream>>>(dmean, W_dec_wl, data_x, dec_dst_w, dec_dst_b,
                                             W_dec_wr, dec_bl, out_w, out_b, out);
}

// Round 7
// 596.099 us; speedup vs baseline: 8.6724x; 1.0326x over previous
//
#include <hip/hip_runtime.h>

#define NDATA 131072
#define NHID  32768
#define NEDGE 524288

typedef __bf16 bf16_t;
typedef __bf16 bf16x4 __attribute__((ext_vector_type(4)));
typedef __bf16 bf16x8 __attribute__((ext_vector_type(8)));
typedef float  f32x4  __attribute__((ext_vector_type(4)));

__device__ __forceinline__ float gelu_f(float x) {
    return 0.5f * x * (1.0f + erff(x * 0.7071067811865476f));
}

// ---------------- weight fp32 -> bf16 conversion ----------------
struct WPtrs { const float* p[8]; };

__global__ __launch_bounds__(256)
void cvt_w_kernel(WPtrs wp, bf16_t* __restrict__ out) {
    const int i = blockIdx.x * 256 + threadIdx.x;   // 8 * 65536 total
    const int wsel = i >> 16, off = i & 65535;
    out[i] = (bf16_t)wp.p[wsel][off];
}

// ---------------- batched CSR build (3 graphs) ----------------
// graph g: 0=dh (n=NHID), 1=hh (n=NHID), 2=hd (n=NDATA)
// cnt/cursor offsets: 0, NHID, 2*NHID ; rp offsets: 0, NHID+1, 2*NHID+2
// scan blocks: g0 [0,32), g1 [32,64), g2 [64,192)

struct EdgePtrs { const int* src[3]; const int* dst[3]; };

__device__ __forceinline__ int cnt_off_of(int g) { return g == 0 ? 0 : (g == 1 ? NHID : 2 * NHID); }
__device__ __forceinline__ int rp_off_of(int g)  { return g == 0 ? 0 : (g == 1 ? NHID + 1 : 2 * NHID + 2); }

__global__ __launch_bounds__(256)
void hist3(EdgePtrs ep, int* __restrict__ cnt_all) {
    const int g = blockIdx.x >> 11;                       // 2048 blocks / graph
    const int i = ((blockIdx.x & 2047) << 8) + threadIdx.x;
    atomicAdd(&cnt_all[cnt_off_of(g) + ep.dst[g][i]], 1);
}

__global__ __launch_bounds__(256)
void scan_blk3(const int* __restrict__ cnt_all, int* __restrict__ pre_all,
               int* __restrict__ blk) {
    __shared__ int sh[256];
    const int bid = blockIdx.x;
    int g, local;
    if (bid < 32)      { g = 0; local = bid; }
    else if (bid < 64) { g = 1; local = bid - 32; }
    else               { g = 2; local = bid - 64; }
    const int t = threadIdx.x;
    const int cbase = cnt_off_of(g) + local * 1024 + t * 4;
    const int pbase = rp_off_of(g)  + local * 1024 + t * 4;
    int4 v = *(const int4*)(cnt_all + cbase);
    sh[t] = v.x + v.y + v.z + v.w;
    __syncthreads();
    for (int off = 1; off < 256; off <<= 1) {
        int other = 0;
        if (t >= off) other = sh[t - off];
        __syncthreads();
        if (t >= off) sh[t] += other;
        __syncthreads();
    }
    const int excl = (t == 0) ? 0 : sh[t - 1];
    int4 o;
    o.x = excl; o.y = o.x + v.x; o.z = o.y + v.y; o.w = o.z + v.z;
    *(int4*)(pre_all + pbase) = o;
    if (t == 255) blk[bid] = sh[255];
}

__global__ __launch_bounds__(256)
void scan_mid3(int* __restrict__ blk) {
    __shared__ int sh[256];
    const int g = blockIdx.x;
    const int off = (g == 0) ? 0 : (g == 1 ? 32 : 64);
    const int nb = (g == 2) ? 128 : 32;
    const int t = threadIdx.x;
    sh[t] = (t < nb) ? blk[off + t] : 0;
    __syncthreads();
    for (int o2 = 1; o2 < 256; o2 <<= 1) {
        int other = 0;
        if (t >= o2) other = sh[t - o2];
        __syncthreads();
        if (t >= o2) sh[t] += other;
        __syncthreads();
    }
    if (t < nb) blk[off + t] = (t == 0) ? 0 : sh[t - 1];
}

__global__ __launch_bounds__(256)
void scan_add3(const int* __restrict__ pre_all, const int* __restrict__ blk,
               int* __restrict__ rp_all, int* __restrict__ cur_all) {
    const int bid = blockIdx.x;
    int g, local;
    if (bid < 32)      { g = 0; local = bid; }
    else if (bid < 64) { g = 1; local = bid - 32; }
    else               { g = 2; local = bid - 64; }
    const int t = threadIdx.x;
    const int off = blk[bid];
    const int pbase = rp_off_of(g)  + local * 1024 + t * 4;
    const int cbase = cnt_off_of(g) + local * 1024 + t * 4;
    int4 v = *(const int4*)(pre_all + pbase);
    v.x += off; v.y += off; v.z += off; v.w += off;
    *(int4*)(rp_all + pbase) = v;
    *(int4*)(cur_all + cbase) = v;
    if (local == 0 && t == 0) {
        const int n = (g == 2) ? NDATA : NHID;
        rp_all[rp_off_of(g) + n] = NEDGE;
    }
}

__global__ __launch_bounds__(256)
void scatter3(EdgePtrs ep, int* __restrict__ cur_all, int* __restrict__ sorted_all) {
    const int g = blockIdx.x >> 11;
    const int i = ((blockIdx.x & 2047) << 8) + threadIdx.x;
    const int p = atomicAdd(&cur_all[cnt_off_of(g) + ep.dst[g][i]], 1);
    sorted_all[(size_t)g * NEDGE + p] = ep.src[g][i];
}

// ---------------- CSR aggregation (mean), bf16 features ----------------
__global__ __launch_bounds__(256)
void csr_gather_mean(const bf16_t* __restrict__ feat, const int* __restrict__ row_ptr,
                     const int* __restrict__ sorted_src, bf16_t* __restrict__ mean, int n) {
    const int lane = threadIdx.x & 63;
    const int half = lane >> 5;
    const int col8 = (lane & 31) * 8;
    const int w = blockIdx.x * 4 + (threadIdx.x >> 6);
    if (w >= n) return;
    const int e0 = row_ptr[w], e1 = row_ptr[w + 1];
    float acc[8] = {0.f, 0.f, 0.f, 0.f, 0.f, 0.f, 0.f, 0.f};
    for (int e = e0 + half; e < e1; e += 2) {
        const int s = sorted_src[e];
        const bf16x8 v = *(const bf16x8*)(feat + (size_t)s * 256 + col8);
        #pragma unroll
        for (int j = 0; j < 8; ++j) acc[j] += (float)v[j];
    }
    #pragma unroll
    for (int j = 0; j < 8; ++j) acc[j] += __shfl_xor(acc[j], 32, 64);
    if (half == 0) {
        const float ic = 1.0f / fmaxf((float)(e1 - e0), 1.0f);
        bf16x8 r;
        #pragma unroll
        for (int j = 0; j < 8; ++j) r[j] = (bf16_t)(acc[j] * ic);
        *(bf16x8*)(mean + (size_t)w * 256 + col8) = r;
    }
}

// ---------------- small-K encoder: wave per node ----------------
template<int K>
__global__ __launch_bounds__(256)
void enc_kernel(const float* __restrict__ x, const float* __restrict__ w,
                const float* __restrict__ b, bf16_t* __restrict__ out, int n) {
    __shared__ float ws[K * 256];
    __shared__ float bs[256];
    const int t = threadIdx.x;
    #pragma unroll
    for (int j = 0; j < K; ++j) ws[j * 256 + t] = w[t * K + j];
    bs[t] = b[t];
    __syncthreads();
    const int lane = t & 63, wv = t >> 6;
    const int f0 = lane * 4;
    const float4 b4 = *(const float4*)(&bs[f0]);
    for (int node = blockIdx.x * 4 + wv; node < n; node += gridDim.x * 4) {
        const float* xr = x + (size_t)node * K;
        float xv[K];
        #pragma unroll
        for (int j = 0; j < K; ++j) xv[j] = xr[j];
        float a0 = b4.x, a1 = b4.y, a2 = b4.z, a3 = b4.w;
        #pragma unroll
        for (int j = 0; j < K; ++j) {
            const float4 w4 = *(const float4*)(&ws[j * 256 + f0]);
            a0 += xv[j] * w4.x; a1 += xv[j] * w4.y;
            a2 += xv[j] * w4.z; a3 += xv[j] * w4.w;
        }
        bf16x4 r;
        r[0] = (bf16_t)gelu_f(a0); r[1] = (bf16_t)gelu_f(a1);
        r[2] = (bf16_t)gelu_f(a2); r[3] = (bf16_t)gelu_f(a3);
        *(bf16x4*)(out + (size_t)node * 256 + f0) = r;
    }
}

// ---------------- MFMA bf16 GEMM ----------------
// C[M,256] = gelu( bias + A1 @ W1^T [+ A2 @ W2^T] )
#define ASTR 40   // LDS row stride in bf16 (80 B)
template<int DUAL>
__global__ __launch_bounds__(256)
void mfma_gemm(const bf16_t* __restrict__ A1, const bf16_t* __restrict__ W1,
               const bf16_t* __restrict__ A2, const bf16_t* __restrict__ W2,
               const float* __restrict__ bias, bf16_t* __restrict__ C) {
    __shared__ bf16_t As[64 * ASTR];
    __shared__ bf16_t Bs[256 * ASTR];
    const int t = threadIdx.x;
    const int w = t >> 6, lane = t & 63;
    const int l15 = lane & 15, l4 = lane >> 4;
    const int m0 = blockIdx.x * 64;

    f32x4 acc[4][4];
    #pragma unroll
    for (int nb = 0; nb < 4; ++nb) {
        const float bv = bias[w * 64 + nb * 16 + l15];
        #pragma unroll
        for (int m = 0; m < 4; ++m) {
            acc[m][nb][0] = bv; acc[m][nb][1] = bv; acc[m][nb][2] = bv; acc[m][nb][3] = bv;
        }
    }

    const int ar = t >> 2, aq = t & 3;
    #pragma unroll
    for (int p = 0; p <= DUAL; ++p) {
        const bf16_t* Ap = p ? A2 : A1;
        const bf16_t* Wp = p ? W2 : W1;
        for (int kt = 0; kt < 8; ++kt) {
            const int k0 = kt * 32;
            __syncthreads();
            *(bf16x8*)(&As[ar * ASTR + aq * 8]) =
                *(const bf16x8*)(Ap + (size_t)(m0 + ar) * 256 + k0 + aq * 8);
            {
                const bf16_t* wrp = Wp + (size_t)t * 256 + k0;
                #pragma unroll
                for (int q = 0; q < 4; ++q)
                    *(bf16x8*)(&Bs[t * ASTR + q * 8]) = *(const bf16x8*)(wrp + q * 8);
            }
            __syncthreads();
            bf16x8 af[4], bfr[4];
            #pragma unroll
            for (int m = 0; m < 4; ++m)
                af[m] = *(const bf16x8*)(&As[(m * 16 + l15) * ASTR + l4 * 8]);
            #pragma unroll
            for (int nb = 0; nb < 4; ++nb)
                bfr[nb] = *(const bf16x8*)(&Bs[(w * 64 + nb * 16 + l15) * ASTR + l4 * 8]);
            #pragma unroll
            for (int m = 0; m < 4; ++m)
                #pragma unroll
                for (int nb = 0; nb < 4; ++nb)
                    acc[m][nb] = __builtin_amdgcn_mfma_f32_16x16x32_bf16(af[m], bfr[nb], acc[m][nb], 0, 0, 0);
        }
    }

    #pragma unroll
    for (int m = 0; m < 4; ++m) {
        #pragma unroll
        for (int nb = 0; nb < 4; ++nb) {
            const int col = w * 64 + nb * 16 + l15;
            #pragma unroll
            for (int i = 0; i < 4; ++i) {
                const int row = m0 + m * 16 + l4 * 4 + i;
                C[(size_t)row * 256 + col] = (bf16_t)gelu_f(acc[m][nb][i]);
            }
        }
    }
}

// ---------------- fused decoder GEMM ----------------
// t = gelu(dec_bl + A1@W1^T + d@W2^T), d = gelu(data_x@Wd^T+bd) on the fly,
// out = t @ ow^T + ob. xs/wds padded to stride 9 (bank-conflict-free);
// sh_out overlaps xs/wds region (dead after last staging barrier).
__global__ __launch_bounds__(256)
void dec_gemm(const bf16_t* __restrict__ A1, const bf16_t* __restrict__ W1,
              const float* __restrict__ xdat, const float* __restrict__ Wd,
              const float* __restrict__ bd, const bf16_t* __restrict__ W2,
              const float* __restrict__ bias, const float* __restrict__ ow,
              const float* __restrict__ ob, float* __restrict__ out) {
    __shared__ __align__(16) char smem[38144];
    bf16_t* As  = (bf16_t*)smem;                        // 5120 B
    bf16_t* Bs  = (bf16_t*)(smem + 5120);               // 20480 B
    float*  xs  = (float*)(smem + 25600);               // 64*9*4  = 2304 B
    float*  wds = (float*)(smem + 27904);               // 256*9*4 = 9216 B
    float*  bds = (float*)(smem + 37120);               // 1024 B
    float (*sh_out)[64][8] = (float(*)[64][8])(smem + 25600);  // 8192 B, overlaps xs/wds

    const int t = threadIdx.x;
    const int w = t >> 6, lane = t & 63;
    const int l15 = lane & 15, l4 = lane >> 4;
    const int m0 = blockIdx.x * 64;

    // stage data_x rows (stride-9) and Wd (stride-9) + bd
    if (t < 128) {
        const float4 v = *(const float4*)(xdat + (size_t)m0 * 8 + t * 4);
        #pragma unroll
        for (int q = 0; q < 4; ++q) {
            const int e = t * 4 + q, r = e >> 3, j = e & 7;
            xs[r * 9 + j] = ((const float*)&v)[q];
        }
    }
    {
        const float4 wa = *(const float4*)(Wd + t * 8);
        const float4 wb = *(const float4*)(Wd + t * 8 + 4);
        wds[t * 9 + 0] = wa.x; wds[t * 9 + 1] = wa.y; wds[t * 9 + 2] = wa.z; wds[t * 9 + 3] = wa.w;
        wds[t * 9 + 4] = wb.x; wds[t * 9 + 5] = wb.y; wds[t * 9 + 6] = wb.z; wds[t * 9 + 7] = wb.w;
        bds[t] = bd[t];
    }
    __syncthreads();

    const int ar = t >> 2, aq = t & 3;
    float xr[8];
    #pragma unroll
    for (int j = 0; j < 8; ++j) xr[j] = xs[ar * 9 + j];

    float ow_reg[8][4];
    #pragma unroll
    for (int o = 0; o < 8; ++o)
        #pragma unroll
        for (int nb = 0; nb < 4; ++nb)
            ow_reg[o][nb] = ow[o * 256 + w * 64 + nb * 16 + l15];

    f32x4 acc[4][4];
    #pragma unroll
    for (int nb = 0; nb < 4; ++nb) {
        const float bv = bias[w * 64 + nb * 16 + l15];
        #pragma unroll
        for (int m = 0; m < 4; ++m) {
            acc[m][nb][0] = bv; acc[m][nb][1] = bv; acc[m][nb][2] = bv; acc[m][nb][3] = bv;
        }
    }

    #pragma unroll
    for (int p = 0; p < 2; ++p) {
        const bf16_t* Wp = p ? W2 : W1;
        for (int kt = 0; kt < 8; ++kt) {
            const int k0 = kt * 32;
            __syncthreads();
            if (p == 0) {
                *(bf16x8*)(&As[ar * ASTR + aq * 8]) =
                    *(const bf16x8*)(A1 + (size_t)(m0 + ar) * 256 + k0 + aq * 8);
            } else {
                bf16x8 dv;
                #pragma unroll
                for (int kk = 0; kk < 8; ++kk) {
                    const int k = k0 + aq * 8 + kk;
                    float val = bds[k];
                    #pragma unroll
                    for (int j = 0; j < 8; ++j) val += xr[j] * wds[k * 9 + j];
                    dv[kk] = (bf16_t)gelu_f(val);
                }
                *(bf16x8*)(&As[ar * ASTR + aq * 8]) = dv;
            }
            {
                const bf16_t* wrp = Wp + (size_t)t * 256 + k0;
                #pragma unroll
                for (int q = 0; q < 4; ++q)
                    *(bf16x8*)(&Bs[t * ASTR + q * 8]) = *(const bf16x8*)(wrp + q * 8);
            }
            __syncthreads();
            bf16x8 af[4], bfr[4];
            #pragma unroll
            for (int m = 0; m < 4; ++m)
                af[m] = *(const bf16x8*)(&As[(m * 16 + l15) * ASTR + l4 * 8]);
            #pragma unroll
            for (int nb = 0; nb < 4; ++nb)
                bfr[nb] = *(const bf16x8*)(&Bs[(w * 64 + nb * 16 + l15) * ASTR + l4 * 8]);
            #pragma unroll
            for (int m = 0; m < 4; ++m)
                #pragma unroll
                for (int nb = 0; nb < 4; ++nb)
                    acc[m][nb] = __builtin_amdgcn_mfma_f32_16x16x32_bf16(af[m], bfr[nb], acc[m][nb], 0, 0, 0);
        }
    }

    // epilogue: t = gelu(acc); out = t @ ow^T (16-lane shuffle + cross-wave LDS reduce)
    #pragma unroll
    for (int m = 0; m < 4; ++m) {
        #pragma unroll
        for (int i = 0; i < 4; ++i) {
            float tv[4];
            #pragma unroll
            for (int nb = 0; nb < 4; ++nb) tv[nb] = gelu_f(acc[m][nb][i]);
            float p[8];
            #pragma unroll
            for (int o = 0; o < 8; ++o)
                p[o] = tv[0] * ow_reg[o][0] + tv[1] * ow_reg[o][1]
                     + tv[2] * ow_reg[o][2] + tv[3] * ow_reg[o][3];
            #pragma unroll
            for (int msk = 1; msk < 16; msk <<= 1)
                #pragma unroll
                for (int o = 0; o < 8; ++o) p[o] += __shfl_xor(p[o], msk, 64);
            if (l15 == 0) {
                const int row = m * 16 + l4 * 4 + i;
                #pragma unroll
                for (int o = 0; o < 8; ++o) (*sh_out)[0][0], ((float(*)[64][8])sh_out)[w][row][o] = p[o];
            }
        }
    }
    __syncthreads();
    #pragma unroll
    for (int q = 0; q < 2; ++q) {
        const int idx = t * 2 + q;
        const int row = idx >> 3, o = idx & 7;
        const float v = ((float(*)[64][8])sh_out)[0][row][o] + ((float(*)[64][8])sh_out)[1][row][o]
                      + ((float(*)[64][8])sh_out)[2][row][o] + ((float(*)[64][8])sh_out)[3][row][o] + ob[o];
        out[(size_t)(m0 + row) * 8 + o] = v;
    }
}

// ---------------- launch ----------------

extern "C" void kernel_launch(void* const* d_in, const int* in_sizes, int n_in,
                              void* d_out, int out_size, void* d_ws, size_t ws_size,
                              hipStream_t stream) {
    const float* data_x   = (const float*)d_in[0];
    const float* hidden_x = (const float*)d_in[1];
    const int* dh_src = (const int*)d_in[2];
    const int* dh_dst = (const int*)d_in[3];
    const int* hh_src = (const int*)d_in[4];
    const int* hh_dst = (const int*)d_in[5];
    const int* hd_src = (const int*)d_in[6];
    const int* hd_dst = (const int*)d_in[7];
    const float* enc_src_w = (const float*)d_in[8];
    const float* enc_src_b = (const float*)d_in[9];
    const float* enc_dst_w = (const float*)d_in[10];
    const float* enc_dst_b = (const float*)d_in[11];
    const float* enc_wl = (const float*)d_in[12];
    const float* enc_bl = (const float*)d_in[13];
    const float* enc_wr = (const float*)d_in[14];
    const float* proc_wl = (const float*)d_in[15];
    const float* proc_bl = (const float*)d_in[16];
    const float* proc_wr = (const float*)d_in[17];
    const float* proc_mlp_w = (const float*)d_in[18];
    const float* proc_mlp_b = (const float*)d_in[19];
    const float* dec_src_w = (const float*)d_in[20];
    const float* dec_src_b = (const float*)d_in[21];
    const float* dec_dst_w = (const float*)d_in[22];
    const float* dec_dst_b = (const float*)d_in[23];
    const float* dec_wl = (const float*)d_in[24];
    const float* dec_bl = (const float*)d_in[25];
    const float* dec_wr = (const float*)d_in[26];
    const float* out_w  = (const float*)d_in[27];
    const float* out_b  = (const float*)d_in[28];
    float* out = (float*)d_out;

    // ---- workspace ----
    bf16_t* h_a   = (bf16_t*)d_ws;                       // NHID*256
    bf16_t* h_b   = h_a + (size_t)NHID * 256;            // NHID*256
    bf16_t* h_msg = h_b + (size_t)NHID * 256;            // NDATA*256
    bf16_t* dmean = h_msg + (size_t)NDATA * 256;         // NDATA*256
    bf16_t* wbuf  = dmean + (size_t)NDATA * 256;         // 8*65536
    int* cnt_all    = (int*)(wbuf + 8 * 65536);          // 2*NHID+NDATA
    int* rp_all     = cnt_all + (2 * NHID + NDATA);      // 2*(NHID+1)+NDATA+1
    int* sorted_all = rp_all + (2 * NHID + NDATA + 3);   // 3*NEDGE
    int* blk_sums   = sorted_all + (size_t)3 * NEDGE;    // 192

    bf16_t* W_enc_wl  = wbuf + 0 * 65536;
    bf16_t* W_enc_wr  = wbuf + 1 * 65536;
    bf16_t* W_proc_wl = wbuf + 2 * 65536;
    bf16_t* W_proc_wr = wbuf + 3 * 65536;
    bf16_t* W_mlp     = wbuf + 4 * 65536;
    bf16_t* W_dec_src = wbuf + 5 * 65536;
    bf16_t* W_dec_wl  = wbuf + 6 * 65536;
    bf16_t* W_dec_wr  = wbuf + 7 * 65536;

    const int* rp_dh = rp_all;
    const int* rp_hh = rp_all + NHID + 1;
    const int* rp_hd = rp_all + 2 * NHID + 2;
    const int* so_dh = sorted_all;
    const int* so_hh = sorted_all + NEDGE;
    const int* so_hd = sorted_all + 2 * (size_t)NEDGE;

    WPtrs wp;
    wp.p[0] = enc_wl;  wp.p[1] = enc_wr;  wp.p[2] = proc_wl; wp.p[3] = proc_wr;
    wp.p[4] = proc_mlp_w; wp.p[5] = dec_src_w; wp.p[6] = dec_wl; wp.p[7] = dec_wr;
    cvt_w_kernel<<<2048, 256, 0, stream>>>(wp, wbuf);

    // ---- batched CSR build for all 3 graphs ----
    EdgePtrs ep;
    ep.src[0] = dh_src; ep.dst[0] = dh_dst;
    ep.src[1] = hh_src; ep.dst[1] = hh_dst;
    ep.src[2] = hd_src; ep.dst[2] = hd_dst;
    hipMemsetAsync(cnt_all, 0, (size_t)(2 * NHID + NDATA) * sizeof(int), stream);
    hist3<<<3 * 2048, 256, 0, stream>>>(ep, cnt_all);
    scan_blk3<<<192, 256, 0, stream>>>(cnt_all, rp_all, blk_sums);
    scan_mid3<<<3, 256, 0, stream>>>(blk_sums);
    scan_add3<<<192, 256, 0, stream>>>(rp_all, blk_sums, rp_all, cnt_all);
    scatter3<<<3 * 2048, 256, 0, stream>>>(ep, cnt_all, sorted_all);

    // ---- encoder ----
    enc_kernel<3><<<512, 256, 0, stream>>>(hidden_x, enc_dst_w, enc_dst_b, h_a, NHID);
    enc_kernel<8><<<2048, 256, 0, stream>>>(data_x, enc_src_w, enc_src_b, h_msg, NDATA);
    csr_gather_mean<<<NHID / 4, 256, 0, stream>>>(h_msg, rp_dh, so_dh, h_b, NHID);
    mfma_gemm<1><<<NHID / 64, 256, 0, stream>>>(h_b, W_enc_wl, h_a, W_enc_wr, enc_bl, h_b);

    // ---- processor ----
    csr_gather_mean<<<NHID / 4, 256, 0, stream>>>(h_b, rp_hh, so_hh, h_a, NHID);
    mfma_gemm<1><<<NHID / 64, 256, 0, stream>>>(h_a, W_proc_wl, h_b, W_proc_wr, proc_bl, h_a);
    mfma_gemm<0><<<NHID / 64, 256, 0, stream>>>(h_a, W_mlp, nullptr, nullptr, proc_mlp_b, h_b);
    mfma_gemm<0><<<NHID / 64, 256, 0, stream>>>(h_b, W_dec_src, nullptr, nullptr, dec_src_b, h_a);

    // ---- decoder (fully fused) ----
    csr_gather_mean<<<NDATA / 4, 256, 0, stream>>>(h_a, rp_hd, so_hd, dmean, NDATA);
    dec_gemm<<<NDATA / 64, 256, 0, stream>>>(dmean, W_dec_wl, data_x, dec_dst_w, dec_dst_b,
                                             W_dec_wr, dec_bl, out_w, out_b, out);
}